// Round 9
// baseline (308.053 us; speedup 1.0000x reference)
//
#include <hip/hip_runtime.h>
#include <hip/hip_bf16.h>

#define FDIM 64
#define BNODES 64          // nodes per bucket (dst >> 6)
#define CHUNK 2048         // edges per hist/fill chunk (391 chunks)
#define HPAD 68            // padded LDS row
#define GCAP 3072          // staged edge-index capacity per bucket (avg 1024, +32 sigma ~1140)

__device__ __forceinline__ unsigned short f2bf(float f) {
    unsigned int u = __float_as_uint(f);
    unsigned int r = (u + 0x7fffu + ((u >> 16) & 1u)) >> 16;   // RNE
    return (unsigned short)r;
}
__device__ __forceinline__ float bflo(unsigned int p) { return __uint_as_float(p << 16); }
__device__ __forceinline__ float bfhi(unsigned int p) { return __uint_as_float(p & 0xffff0000u); }

// ---- cast fp32 -> bf16 (features), 4 elems/thread ----
__global__ __launch_bounds__(256) void cast_bf16(const float* __restrict__ x,
                                                 unsigned short* __restrict__ xb, int n4) {
    int i = blockIdx.x * blockDim.x + threadIdx.x;
    if (i < n4) {
        float4 v = ((const float4*)x)[i];
        uint2 o;
        o.x = (unsigned int)f2bf(v.x) | ((unsigned int)f2bf(v.y) << 16);
        o.y = (unsigned int)f2bf(v.z) | ((unsigned int)f2bf(v.w) << 16);
        ((uint2*)xb)[i] = o;
    }
}

// ---- pass 1: per-chunk LDS histogram -> padded global bucket totals ----
// bucket_total_pad[b*16] : one counter per 64B line (no same-line atomic serialization)
__global__ __launch_bounds__(256) void bucket_hist_total(const int* __restrict__ dst,
                                                         int* __restrict__ bucket_total_pad,
                                                         int n_edges, int nbuck) {
    __shared__ int lh[1024];
    int chunk = blockIdx.x;
    for (int i = threadIdx.x; i < nbuck; i += 256) lh[i] = 0;
    __syncthreads();
    int beg = chunk * CHUNK;
    int end = min(beg + CHUNK, n_edges);
    for (int e = beg + threadIdx.x; e < end; e += 256)
        atomicAdd(&lh[dst[e] >> 6], 1);
    __syncthreads();
    for (int i = threadIdx.x; i < nbuck; i += 256) {
        int v = lh[i];
        if (v) atomicAdd(&bucket_total_pad[(size_t)i * 16], v);
    }
}

// ---- pass 2: exclusive scan of bucket totals -> bucket_start + padded cursors ----
__global__ __launch_bounds__(1024) void scan_buckets(const int* __restrict__ bucket_total_pad,
                                                     int* __restrict__ bucket_start,
                                                     int* __restrict__ cursor_pad,
                                                     int* __restrict__ row_ptr,
                                                     int nbuck, int n_nodes, int n_edges) {
    __shared__ int s[1024];
    int t = threadIdx.x;
    int v = (t < nbuck) ? bucket_total_pad[(size_t)t * 16] : 0;
    s[t] = v;
    __syncthreads();
    for (int off = 1; off < 1024; off <<= 1) {
        int u = (t >= off) ? s[t - off] : 0;
        __syncthreads();
        s[t] += u;
        __syncthreads();
    }
    if (t < nbuck) {
        int ex = s[t] - v;
        bucket_start[t] = ex;
        cursor_pad[(size_t)t * 16] = ex;
    }
    if (t == 0) { bucket_start[nbuck] = n_edges; row_ptr[n_nodes] = n_edges; }
}

// ---- pass 3: fill packed edges via padded global cursors ----
__global__ __launch_bounds__(256) void bucket_fill_atomic(const int* __restrict__ src,
                                                          const int* __restrict__ dst,
                                                          int* __restrict__ cursor_pad,
                                                          unsigned int* __restrict__ packed,
                                                          int n_edges) {
    int beg = blockIdx.x * CHUNK;
    int end = min(beg + CHUNK, n_edges);
    for (int e = beg + threadIdx.x; e < end; e += 256) {
        int d = dst[e];
        int b = d >> 6;
        int pos = atomicAdd(&cursor_pad[(size_t)b * 16], 1);
        packed[pos] = (unsigned int)src[e] | ((unsigned int)(d & 63) << 16);
    }
}

// ---- pass 4: within-bucket sort to node granularity + row_ptr emit ----
__global__ __launch_bounds__(256) void sort_bucket(const unsigned int* __restrict__ packed,
                                                   const int* __restrict__ bucket_start,
                                                   int* __restrict__ src_sorted,
                                                   int* __restrict__ row_ptr, int n_nodes) {
    __shared__ int cnt[BNODES];
    __shared__ int cur[BNODES];
    int b = blockIdx.x;
    int beg = bucket_start[b], end = bucket_start[b + 1];
    if (threadIdx.x < BNODES) cnt[threadIdx.x] = 0;
    __syncthreads();
    for (int e = beg + threadIdx.x; e < end; e += 256)
        atomicAdd(&cnt[packed[e] >> 16], 1);
    __syncthreads();
    if (threadIdx.x < 64) {       // one wave: shfl inclusive scan over 64 degrees
        int v = cnt[threadIdx.x];
        int inc = v;
#pragma unroll
        for (int off = 1; off < 64; off <<= 1) {
            int u = __shfl_up(inc, off, 64);
            if (threadIdx.x >= off) inc += u;
        }
        cur[threadIdx.x] = beg + inc - v;     // exclusive
        int node = b * BNODES + threadIdx.x;
        if (node < n_nodes) row_ptr[node] = beg + inc - v;
    }
    __syncthreads();
    for (int e = beg + threadIdx.x; e < end; e += 256) {
        unsigned int p = packed[e];
        int pos = atomicAdd(&cur[p >> 16], 1);
        src_sorted[pos] = (int)(p & 0xFFFFu);
    }
}

// ---- fused conv: gather (bf16 rows -> fp32 LDS tile) + 2-layer MLP (+ optional final) ----
// One block per bucket (64 nodes). Edge indices staged into LDS aliased with sh:
// accumulators stay in registers across all 4 node-passes; one sync separates the
// last sidx read from the sh overwrite.
__global__ __launch_bounds__(256) void gin_tile(const unsigned short* __restrict__ xb,
        const int* __restrict__ row_ptr,
        const int* __restrict__ src_sorted,
        const float* __restrict__ W1, const float* __restrict__ b1,
        const float* __restrict__ W2, const float* __restrict__ b2,
        const float* __restrict__ Wl, const float* __restrict__ bl,
        unsigned short* __restrict__ y, float* __restrict__ out,
        int n_nodes, int do_final) {
    __shared__ float sW1[FDIM * FDIM];
    __shared__ float sW2[FDIM * FDIM];
    __shared__ float sh[64 * HPAD];          // 17408 floats >= GCAP ints
    __shared__ float sb1[FDIM], sb2[FDIM];
    __shared__ float sWl[FDIM * 10];
    __shared__ float sbl[16];
    int* sidx = (int*)sh;

    int tid = threadIdx.x;
    int base = blockIdx.x * 64;

    // stage weights (disjoint LDS; overlaps gather index staging)
    {
        const float4* W14 = (const float4*)W1;
        const float4* W24 = (const float4*)W2;
        float4* s1 = (float4*)sW1;
        float4* s2 = (float4*)sW2;
#pragma unroll
        for (int k = 0; k < 4; k++) {
            s1[tid + k * 256] = W14[tid + k * 256];
            s2[tid + k * 256] = W24[tid + k * 256];
        }
    }
    if (tid < FDIM) { sb1[tid] = b1[tid]; sb2[tid] = b2[tid]; }
    if (do_final) {
        for (int i = tid; i < FDIM * 10; i += 256) sWl[i] = Wl[i];
        if (tid < 10) sbl[tid] = bl[tid];
    }
    // stage this bucket's edge indices (coalesced)
    int ebeg = row_ptr[base];
    int eend = row_ptr[min(base + 64, n_nodes)];
    int total = eend - ebeg;
    int cnt = min(total, GCAP);
    for (int i = tid; i < cnt; i += 256) sidx[i] = src_sorted[ebeg + i];
    __syncthreads();

    // gather: 4 passes x 16 nodes, 16 threads/node, fp32 accum in registers
    int c = (tid & 15) * 4;
    float4 acc[4];
#pragma unroll
    for (int p = 0; p < 4; p++) {
        int node = base + p * 16 + (tid >> 4);
        float4 a = make_float4(0.f, 0.f, 0.f, 0.f);
        if (node < n_nodes) {
            uint2 sv = *(const uint2*)(xb + (size_t)node * FDIM + c);
            a.x = bflo(sv.x); a.y = bfhi(sv.x);
            a.z = bflo(sv.y); a.w = bfhi(sv.y);
            int dbeg = row_ptr[node] - ebeg;
            int dend = row_ptr[node + 1] - ebeg;
            int dmid = min(dend, cnt);
            int e = dbeg;
            for (; e + 7 < dmid; e += 8) {
                int s[8];
#pragma unroll
                for (int j = 0; j < 8; j++) s[j] = sidx[e + j];
                uint2 v[8];
#pragma unroll
                for (int j = 0; j < 8; j++) v[j] = *(const uint2*)(xb + (size_t)s[j] * FDIM + c);
#pragma unroll
                for (int j = 0; j < 8; j++) {
                    a.x += bflo(v[j].x); a.y += bfhi(v[j].x);
                    a.z += bflo(v[j].y); a.w += bfhi(v[j].y);
                }
            }
            if (e + 3 < dmid) {
                int s[4];
#pragma unroll
                for (int j = 0; j < 4; j++) s[j] = sidx[e + j];
                uint2 v[4];
#pragma unroll
                for (int j = 0; j < 4; j++) v[j] = *(const uint2*)(xb + (size_t)s[j] * FDIM + c);
#pragma unroll
                for (int j = 0; j < 4; j++) {
                    a.x += bflo(v[j].x); a.y += bfhi(v[j].x);
                    a.z += bflo(v[j].y); a.w += bfhi(v[j].y);
                }
                e += 4;
            }
            for (; e < dmid; e++) {
                uint2 v = *(const uint2*)(xb + (size_t)sidx[e] * FDIM + c);
                a.x += bflo(v.x); a.y += bfhi(v.x);
                a.z += bflo(v.y); a.w += bfhi(v.y);
            }
            for (; e < dend; e++) {            // overflow tail (virtually never)
                uint2 v = *(const uint2*)(xb + (size_t)src_sorted[ebeg + e] * FDIM + c);
                a.x += bflo(v.x); a.y += bfhi(v.x);
                a.z += bflo(v.y); a.w += bfhi(v.y);
            }
        }
        acc[p] = a;
    }
    __syncthreads();   // all sidx reads done; sh may be overwritten
#pragma unroll
    for (int p = 0; p < 4; p++) {
        int r = p * 16 + (tid >> 4);
        *(float4*)(&sh[r * HPAD + c]) = acc[p];
    }
    __syncthreads();

    // MLP: 4 nodes/thread register-blocked
    int ng = tid >> 4;
    int jq = (tid & 15) * 4;
    int r0 = ng * 4;

    float a[4][4];
#pragma unroll
    for (int i = 0; i < 4; i++) {
        a[i][0] = sb1[jq]; a[i][1] = sb1[jq + 1];
        a[i][2] = sb1[jq + 2]; a[i][3] = sb1[jq + 3];
    }
#pragma unroll
    for (int k0 = 0; k0 < FDIM; k0 += 4) {
        float4 w0 = *(float4*)(&sW1[(k0 + 0) * FDIM + jq]);
        float4 w1 = *(float4*)(&sW1[(k0 + 1) * FDIM + jq]);
        float4 w2 = *(float4*)(&sW1[(k0 + 2) * FDIM + jq]);
        float4 w3 = *(float4*)(&sW1[(k0 + 3) * FDIM + jq]);
#pragma unroll
        for (int i = 0; i < 4; i++) {
            float4 hv = *(float4*)(&sh[(r0 + i) * HPAD + k0]);
            a[i][0] += hv.x * w0.x + hv.y * w1.x + hv.z * w2.x + hv.w * w3.x;
            a[i][1] += hv.x * w0.y + hv.y * w1.y + hv.z * w2.y + hv.w * w3.y;
            a[i][2] += hv.x * w0.z + hv.y * w1.z + hv.z * w2.z + hv.w * w3.z;
            a[i][3] += hv.x * w0.w + hv.y * w1.w + hv.z * w2.w + hv.w * w3.w;
        }
    }
    __syncthreads();
#pragma unroll
    for (int i = 0; i < 4; i++) {
        float4 g;
        g.x = fmaxf(a[i][0], 0.f); g.y = fmaxf(a[i][1], 0.f);
        g.z = fmaxf(a[i][2], 0.f); g.w = fmaxf(a[i][3], 0.f);
        *(float4*)(&sh[(r0 + i) * HPAD + jq]) = g;
    }
    __syncthreads();

#pragma unroll
    for (int i = 0; i < 4; i++) {
        a[i][0] = sb2[jq]; a[i][1] = sb2[jq + 1];
        a[i][2] = sb2[jq + 2]; a[i][3] = sb2[jq + 3];
    }
#pragma unroll
    for (int k0 = 0; k0 < FDIM; k0 += 4) {
        float4 w0 = *(float4*)(&sW2[(k0 + 0) * FDIM + jq]);
        float4 w1 = *(float4*)(&sW2[(k0 + 1) * FDIM + jq]);
        float4 w2 = *(float4*)(&sW2[(k0 + 2) * FDIM + jq]);
        float4 w3 = *(float4*)(&sW2[(k0 + 3) * FDIM + jq]);
#pragma unroll
        for (int i = 0; i < 4; i++) {
            float4 gv = *(float4*)(&sh[(r0 + i) * HPAD + k0]);
            a[i][0] += gv.x * w0.x + gv.y * w1.x + gv.z * w2.x + gv.w * w3.x;
            a[i][1] += gv.x * w0.y + gv.y * w1.y + gv.z * w2.y + gv.w * w3.y;
            a[i][2] += gv.x * w0.z + gv.y * w1.z + gv.z * w2.z + gv.w * w3.z;
            a[i][3] += gv.x * w0.w + gv.y * w1.w + gv.z * w2.w + gv.w * w3.w;
        }
    }

    if (!do_final) {
#pragma unroll
        for (int i = 0; i < 4; i++) {
            int node = base + r0 + i;
            if (node < n_nodes) {
                float o0 = fmaxf(a[i][0], 0.f), o1 = fmaxf(a[i][1], 0.f);
                float o2 = fmaxf(a[i][2], 0.f), o3 = fmaxf(a[i][3], 0.f);
                uint2 p;
                p.x = (unsigned int)f2bf(o0) | ((unsigned int)f2bf(o1) << 16);
                p.y = (unsigned int)f2bf(o2) | ((unsigned int)f2bf(o3) << 16);
                *(uint2*)(y + (size_t)node * FDIM + jq) = p;
            }
        }
    } else {
        __syncthreads();
#pragma unroll
        for (int i = 0; i < 4; i++) {
            float4 o;
            o.x = fmaxf(a[i][0], 0.f); o.y = fmaxf(a[i][1], 0.f);
            o.z = fmaxf(a[i][2], 0.f); o.w = fmaxf(a[i][3], 0.f);
            *(float4*)(&sh[(r0 + i) * HPAD + jq]) = o;
        }
        __syncthreads();
        for (int i = tid; i < 64 * 10; i += 256) {
            int nl = i / 10, cc = i % 10;
            int node = base + nl;
            if (node < n_nodes) {
                float s = sbl[cc];
#pragma unroll
                for (int k0 = 0; k0 < FDIM; k0 += 4) {
                    float4 hv = *(float4*)(&sh[nl * HPAD + k0]);
                    s += hv.x * sWl[(k0 + 0) * 10 + cc] + hv.y * sWl[(k0 + 1) * 10 + cc]
                       + hv.z * sWl[(k0 + 2) * 10 + cc] + hv.w * sWl[(k0 + 3) * 10 + cc];
                }
                out[(size_t)node * 10 + cc] = s;
            }
        }
    }
}

extern "C" void kernel_launch(void* const* d_in, const int* in_sizes, int n_in,
                              void* d_out, int out_size, void* d_ws, size_t ws_size,
                              hipStream_t stream) {
    const float* features = (const float*)d_in[0];
    const int* edges = (const int*)d_in[1];
    int n_nodes = in_sizes[0] / FDIM;          // 50000
    int n_edges = in_sizes[1] / 2;             // 800000
    const int* src = edges;
    const int* dst = edges + n_edges;

    int nbuck = (n_nodes + BNODES - 1) / BNODES;     // 782
    int nchunks = (n_edges + CHUNK - 1) / CHUNK;     // 391

    // workspace: bucket_total_pad | cursor_pad | bucket_start | row_ptr | packed | src_sorted | bf16 bufs
    int* bucket_total_pad = (int*)d_ws;                              // nbuck*16
    int* cursor_pad = bucket_total_pad + (size_t)nbuck * 16;         // nbuck*16
    int* bucket_start = cursor_pad + (size_t)nbuck * 16;             // nbuck+1
    int* row_ptr = bucket_start + nbuck + 1;                         // n_nodes+1
    unsigned int* packed = (unsigned int*)(row_ptr + n_nodes + 1);   // n_edges
    int* src_sorted = (int*)(packed + n_edges);                      // n_edges
    size_t int_elems = 32 * (size_t)nbuck + (size_t)nbuck + 1
                       + (size_t)n_nodes + 1 + 2 * (size_t)n_edges;
    int_elems = (int_elems + 3) & ~(size_t)3;
    size_t buf_elems = (size_t)n_nodes * FDIM;
    unsigned short* xb0 = (unsigned short*)((int*)d_ws + int_elems);
    unsigned short* yA  = xb0 + buf_elems;
    unsigned short* yB  = yA + buf_elems;

    dim3 bs(256);
    dim3 gs_cast(((int)(buf_elems / 4) + 255) / 256);

    // --- cast features to bf16; zero padded bucket totals ---
    hipMemsetAsync(bucket_total_pad, 0, (size_t)nbuck * 16 * sizeof(int), stream);
    cast_bf16<<<gs_cast, bs, 0, stream>>>(features, xb0, (int)(buf_elems / 4));

    // --- build node-grouped CSR (4 kernels) ---
    bucket_hist_total<<<nchunks, 256, 0, stream>>>(dst, bucket_total_pad, n_edges, nbuck);
    scan_buckets<<<1, 1024, 0, stream>>>(bucket_total_pad, bucket_start, cursor_pad,
                                         row_ptr, nbuck, n_nodes, n_edges);
    bucket_fill_atomic<<<nchunks, 256, 0, stream>>>(src, dst, cursor_pad, packed, n_edges);
    sort_bucket<<<nbuck, 256, 0, stream>>>(packed, bucket_start, src_sorted, row_ptr, n_nodes);

    // --- 3 fused GIN convs (last fuses the final linear) ---
    const float* Wl = (const float*)d_in[14];
    const float* bl = (const float*)d_in[15];
    const unsigned short* x_cur = xb0;
    unsigned short* outs[3] = {yA, yB, yA};
    for (int conv = 0; conv < 3; conv++) {
        const float* W1 = (const float*)d_in[2 + 4 * conv];
        const float* b1 = (const float*)d_in[3 + 4 * conv];
        const float* W2 = (const float*)d_in[4 + 4 * conv];
        const float* b2 = (const float*)d_in[5 + 4 * conv];
        int fin = (conv == 2) ? 1 : 0;

        gin_tile<<<nbuck, bs, 0, stream>>>(x_cur, row_ptr, src_sorted,
                                           W1, b1, W2, b2, Wl, bl,
                                           outs[conv], (float*)d_out, n_nodes, fin);
        x_cur = outs[conv];
    }
}

// Round 10
// 283.232 us; speedup vs baseline: 1.0876x; 1.0876x over previous
//
#include <hip/hip_runtime.h>
#include <hip/hip_bf16.h>

#define FDIM 64
#define BNODES 64          // nodes per bucket (dst >> 6)
#define CHUNK 2048         // edges per hist/fill chunk (391 chunks)
#define HPAD 68            // padded LDS row
#define GCAP 2048          // staged edge-index capacity per gather block (32 nodes, avg ~512)

__device__ __forceinline__ unsigned short f2bf(float f) {
    unsigned int u = __float_as_uint(f);
    unsigned int r = (u + 0x7fffu + ((u >> 16) & 1u)) >> 16;   // RNE
    return (unsigned short)r;
}
__device__ __forceinline__ float bflo(unsigned int p) { return __uint_as_float(p << 16); }
__device__ __forceinline__ float bfhi(unsigned int p) { return __uint_as_float(p & 0xffff0000u); }

// ---- cast fp32 -> bf16 (features), 4 elems/thread ----
__global__ __launch_bounds__(256) void cast_bf16(const float* __restrict__ x,
                                                 unsigned short* __restrict__ xb, int n4) {
    int i = blockIdx.x * blockDim.x + threadIdx.x;
    if (i < n4) {
        float4 v = ((const float4*)x)[i];
        uint2 o;
        o.x = (unsigned int)f2bf(v.x) | ((unsigned int)f2bf(v.y) << 16);
        o.y = (unsigned int)f2bf(v.z) | ((unsigned int)f2bf(v.w) << 16);
        ((uint2*)xb)[i] = o;
    }
}

// ---- pass 1: per-chunk LDS histogram -> padded global bucket totals ----
__global__ __launch_bounds__(256) void bucket_hist_total(const int* __restrict__ dst,
                                                         int* __restrict__ bucket_total_pad,
                                                         int n_edges, int nbuck) {
    __shared__ int lh[1024];
    int chunk = blockIdx.x;
    for (int i = threadIdx.x; i < nbuck; i += 256) lh[i] = 0;
    __syncthreads();
    int beg = chunk * CHUNK;
    int end = min(beg + CHUNK, n_edges);
    for (int e = beg + threadIdx.x; e < end; e += 256)
        atomicAdd(&lh[dst[e] >> 6], 1);
    __syncthreads();
    for (int i = threadIdx.x; i < nbuck; i += 256) {
        int v = lh[i];
        if (v) atomicAdd(&bucket_total_pad[(size_t)i * 16], v);
    }
}

// ---- pass 2: exclusive scan of bucket totals -> bucket_start + padded cursors ----
__global__ __launch_bounds__(1024) void scan_buckets(const int* __restrict__ bucket_total_pad,
                                                     int* __restrict__ bucket_start,
                                                     int* __restrict__ cursor_pad,
                                                     int* __restrict__ row_ptr,
                                                     int nbuck, int n_nodes, int n_edges) {
    __shared__ int s[1024];
    int t = threadIdx.x;
    int v = (t < nbuck) ? bucket_total_pad[(size_t)t * 16] : 0;
    s[t] = v;
    __syncthreads();
    for (int off = 1; off < 1024; off <<= 1) {
        int u = (t >= off) ? s[t - off] : 0;
        __syncthreads();
        s[t] += u;
        __syncthreads();
    }
    if (t < nbuck) {
        int ex = s[t] - v;
        bucket_start[t] = ex;
        cursor_pad[(size_t)t * 16] = ex;
    }
    if (t == 0) { bucket_start[nbuck] = n_edges; row_ptr[n_nodes] = n_edges; }
}

// ---- pass 3: fill packed edges via padded global cursors ----
__global__ __launch_bounds__(256) void bucket_fill_atomic(const int* __restrict__ src,
                                                          const int* __restrict__ dst,
                                                          int* __restrict__ cursor_pad,
                                                          unsigned int* __restrict__ packed,
                                                          int n_edges) {
    int beg = blockIdx.x * CHUNK;
    int end = min(beg + CHUNK, n_edges);
    for (int e = beg + threadIdx.x; e < end; e += 256) {
        int d = dst[e];
        int b = d >> 6;
        int pos = atomicAdd(&cursor_pad[(size_t)b * 16], 1);
        packed[pos] = (unsigned int)src[e] | ((unsigned int)(d & 63) << 16);
    }
}

// ---- pass 4: within-bucket sort to node granularity + row_ptr emit ----
__global__ __launch_bounds__(256) void sort_bucket(const unsigned int* __restrict__ packed,
                                                   const int* __restrict__ bucket_start,
                                                   int* __restrict__ src_sorted,
                                                   int* __restrict__ row_ptr, int n_nodes) {
    __shared__ int cnt[BNODES];
    __shared__ int cur[BNODES];
    int b = blockIdx.x;
    int beg = bucket_start[b], end = bucket_start[b + 1];
    if (threadIdx.x < BNODES) cnt[threadIdx.x] = 0;
    __syncthreads();
    for (int e = beg + threadIdx.x; e < end; e += 256)
        atomicAdd(&cnt[packed[e] >> 16], 1);
    __syncthreads();
    if (threadIdx.x < 64) {       // one wave: shfl inclusive scan over 64 degrees
        int v = cnt[threadIdx.x];
        int inc = v;
#pragma unroll
        for (int off = 1; off < 64; off <<= 1) {
            int u = __shfl_up(inc, off, 64);
            if (threadIdx.x >= off) inc += u;
        }
        cur[threadIdx.x] = beg + inc - v;     // exclusive
        int node = b * BNODES + threadIdx.x;
        if (node < n_nodes) row_ptr[node] = beg + inc - v;
    }
    __syncthreads();
    for (int e = beg + threadIdx.x; e < end; e += 256) {
        unsigned int p = packed[e];
        int pos = atomicAdd(&cur[p >> 16], 1);
        src_sorted[pos] = (int)(p & 0xFFFFu);
    }
}

// gather (bf16 in/out, fp32 accum): 32 nodes/block, 8 threads/node, 16B/lane loads.
// Block's edge indices staged into LDS (coalesced); rows unrolled 8-deep.
__global__ __launch_bounds__(256) void gather_bf16(const unsigned short* __restrict__ xb,
                                                   const int* __restrict__ row_ptr,
                                                   const int* __restrict__ src_sorted,
                                                   unsigned short* __restrict__ hb,
                                                   int n_nodes) {
    __shared__ int sidx[GCAP];
    int base = blockIdx.x * 32;
    int ebeg = row_ptr[base];
    int eend = row_ptr[min(base + 32, n_nodes)];
    int total = eend - ebeg;
    int cnt = min(total, GCAP);
    for (int i = threadIdx.x; i < cnt; i += 256) sidx[i] = src_sorted[ebeg + i];
    __syncthreads();

    int t = threadIdx.x;
    int node = base + (t >> 3);
    if (node >= n_nodes) return;
    int c = (t & 7) * 8;                  // 8 bf16 = 16B per lane
    int dbeg = row_ptr[node] - ebeg;
    int dend = row_ptr[node + 1] - ebeg;
    int dmid = (total <= GCAP) ? dend : min(dend, cnt);

    float acc[8];
    {
        uint4 v = *(const uint4*)(xb + (size_t)node * FDIM + c);
        acc[0] = bflo(v.x); acc[1] = bfhi(v.x);
        acc[2] = bflo(v.y); acc[3] = bfhi(v.y);
        acc[4] = bflo(v.z); acc[5] = bfhi(v.z);
        acc[6] = bflo(v.w); acc[7] = bfhi(v.w);
    }

    int e = dbeg;
    for (; e + 7 < dmid; e += 8) {
        int s[8];
#pragma unroll
        for (int j = 0; j < 8; j++) s[j] = sidx[e + j];
        uint4 v[8];
#pragma unroll
        for (int j = 0; j < 8; j++) v[j] = *(const uint4*)(xb + (size_t)s[j] * FDIM + c);
#pragma unroll
        for (int j = 0; j < 8; j++) {
            acc[0] += bflo(v[j].x); acc[1] += bfhi(v[j].x);
            acc[2] += bflo(v[j].y); acc[3] += bfhi(v[j].y);
            acc[4] += bflo(v[j].z); acc[5] += bfhi(v[j].z);
            acc[6] += bflo(v[j].w); acc[7] += bfhi(v[j].w);
        }
    }
    if (e + 3 < dmid) {
        int s[4];
#pragma unroll
        for (int j = 0; j < 4; j++) s[j] = sidx[e + j];
        uint4 v[4];
#pragma unroll
        for (int j = 0; j < 4; j++) v[j] = *(const uint4*)(xb + (size_t)s[j] * FDIM + c);
#pragma unroll
        for (int j = 0; j < 4; j++) {
            acc[0] += bflo(v[j].x); acc[1] += bfhi(v[j].x);
            acc[2] += bflo(v[j].y); acc[3] += bfhi(v[j].y);
            acc[4] += bflo(v[j].z); acc[5] += bfhi(v[j].z);
            acc[6] += bflo(v[j].w); acc[7] += bfhi(v[j].w);
        }
        e += 4;
    }
    for (; e < dmid; e++) {
        uint4 v = *(const uint4*)(xb + (size_t)sidx[e] * FDIM + c);
        acc[0] += bflo(v.x); acc[1] += bfhi(v.x);
        acc[2] += bflo(v.y); acc[3] += bfhi(v.y);
        acc[4] += bflo(v.z); acc[5] += bfhi(v.z);
        acc[6] += bflo(v.w); acc[7] += bfhi(v.w);
    }
    for (; e < dend; e++) {               // overflow tail (virtually never)
        uint4 v = *(const uint4*)(xb + (size_t)src_sorted[ebeg + e] * FDIM + c);
        acc[0] += bflo(v.x); acc[1] += bfhi(v.x);
        acc[2] += bflo(v.y); acc[3] += bfhi(v.y);
        acc[4] += bflo(v.z); acc[5] += bfhi(v.z);
        acc[6] += bflo(v.w); acc[7] += bfhi(v.w);
    }

    uint4 p;
    p.x = (unsigned int)f2bf(acc[0]) | ((unsigned int)f2bf(acc[1]) << 16);
    p.y = (unsigned int)f2bf(acc[2]) | ((unsigned int)f2bf(acc[3]) << 16);
    p.z = (unsigned int)f2bf(acc[4]) | ((unsigned int)f2bf(acc[5]) << 16);
    p.w = (unsigned int)f2bf(acc[6]) | ((unsigned int)f2bf(acc[7]) << 16);
    *(uint4*)(hb + (size_t)node * FDIM + c) = p;
}

// MLP over a 64-node tile, 4 nodes/thread register-blocked; fp32 math, bf16 I/O.
__global__ __launch_bounds__(256) void mlp_tile(const unsigned short* __restrict__ xb,
        const float* __restrict__ W1, const float* __restrict__ b1,
        const float* __restrict__ W2, const float* __restrict__ b2,
        const float* __restrict__ Wl, const float* __restrict__ bl,
        unsigned short* __restrict__ y, float* __restrict__ out,
        int n_nodes, int do_final) {
    __shared__ float sW1[FDIM * FDIM];
    __shared__ float sW2[FDIM * FDIM];
    __shared__ float sh[64 * HPAD];
    __shared__ float sb1[FDIM], sb2[FDIM];
    __shared__ float sWl[FDIM * 10];
    __shared__ float sbl[16];

    int tid = threadIdx.x;
    int base = blockIdx.x * 64;

    {
        const float4* W14 = (const float4*)W1;
        const float4* W24 = (const float4*)W2;
        float4* s1 = (float4*)sW1;
        float4* s2 = (float4*)sW2;
#pragma unroll
        for (int k = 0; k < 4; k++) {
            s1[tid + k * 256] = W14[tid + k * 256];
            s2[tid + k * 256] = W24[tid + k * 256];
        }
    }
    if (tid < FDIM) { sb1[tid] = b1[tid]; sb2[tid] = b2[tid]; }
    if (do_final) {
        for (int i = tid; i < FDIM * 10; i += 256) sWl[i] = Wl[i];
        if (tid < 10) sbl[tid] = bl[tid];
    }
    // stage h tile from bf16: 64 rows x 16 uint2, 4 per thread, coalesced
    {
#pragma unroll
        for (int k = 0; k < 4; k++) {
            int idx = tid + k * 256;
            int r = idx >> 4, q = (idx & 15);
            int node = base + r;
            uint2 v = make_uint2(0u, 0u);
            if (node < n_nodes) v = *(const uint2*)(xb + (size_t)node * FDIM + q * 4);
            float4 f;
            f.x = bflo(v.x); f.y = bfhi(v.x);
            f.z = bflo(v.y); f.w = bfhi(v.y);
            *(float4*)(&sh[r * HPAD + q * 4]) = f;
        }
    }
    __syncthreads();

    int ng = tid >> 4;
    int jq = (tid & 15) * 4;
    int r0 = ng * 4;

    float a[4][4];
#pragma unroll
    for (int i = 0; i < 4; i++) {
        a[i][0] = sb1[jq]; a[i][1] = sb1[jq + 1];
        a[i][2] = sb1[jq + 2]; a[i][3] = sb1[jq + 3];
    }
#pragma unroll
    for (int k0 = 0; k0 < FDIM; k0 += 4) {
        float4 w0 = *(float4*)(&sW1[(k0 + 0) * FDIM + jq]);
        float4 w1 = *(float4*)(&sW1[(k0 + 1) * FDIM + jq]);
        float4 w2 = *(float4*)(&sW1[(k0 + 2) * FDIM + jq]);
        float4 w3 = *(float4*)(&sW1[(k0 + 3) * FDIM + jq]);
#pragma unroll
        for (int i = 0; i < 4; i++) {
            float4 hv = *(float4*)(&sh[(r0 + i) * HPAD + k0]);
            a[i][0] += hv.x * w0.x + hv.y * w1.x + hv.z * w2.x + hv.w * w3.x;
            a[i][1] += hv.x * w0.y + hv.y * w1.y + hv.z * w2.y + hv.w * w3.y;
            a[i][2] += hv.x * w0.z + hv.y * w1.z + hv.z * w2.z + hv.w * w3.z;
            a[i][3] += hv.x * w0.w + hv.y * w1.w + hv.z * w2.w + hv.w * w3.w;
        }
    }
    __syncthreads();
#pragma unroll
    for (int i = 0; i < 4; i++) {
        float4 g;
        g.x = fmaxf(a[i][0], 0.f); g.y = fmaxf(a[i][1], 0.f);
        g.z = fmaxf(a[i][2], 0.f); g.w = fmaxf(a[i][3], 0.f);
        *(float4*)(&sh[(r0 + i) * HPAD + jq]) = g;
    }
    __syncthreads();

#pragma unroll
    for (int i = 0; i < 4; i++) {
        a[i][0] = sb2[jq]; a[i][1] = sb2[jq + 1];
        a[i][2] = sb2[jq + 2]; a[i][3] = sb2[jq + 3];
    }
#pragma unroll
    for (int k0 = 0; k0 < FDIM; k0 += 4) {
        float4 w0 = *(float4*)(&sW2[(k0 + 0) * FDIM + jq]);
        float4 w1 = *(float4*)(&sW2[(k0 + 1) * FDIM + jq]);
        float4 w2 = *(float4*)(&sW2[(k0 + 2) * FDIM + jq]);
        float4 w3 = *(float4*)(&sW2[(k0 + 3) * FDIM + jq]);
#pragma unroll
        for (int i = 0; i < 4; i++) {
            float4 gv = *(float4*)(&sh[(r0 + i) * HPAD + k0]);
            a[i][0] += gv.x * w0.x + gv.y * w1.x + gv.z * w2.x + gv.w * w3.x;
            a[i][1] += gv.x * w0.y + gv.y * w1.y + gv.z * w2.y + gv.w * w3.y;
            a[i][2] += gv.x * w0.z + gv.y * w1.z + gv.z * w2.z + gv.w * w3.z;
            a[i][3] += gv.x * w0.w + gv.y * w1.w + gv.z * w2.w + gv.w * w3.w;
        }
    }

    if (!do_final) {
#pragma unroll
        for (int i = 0; i < 4; i++) {
            int node = base + r0 + i;
            if (node < n_nodes) {
                float o0 = fmaxf(a[i][0], 0.f), o1 = fmaxf(a[i][1], 0.f);
                float o2 = fmaxf(a[i][2], 0.f), o3 = fmaxf(a[i][3], 0.f);
                uint2 p;
                p.x = (unsigned int)f2bf(o0) | ((unsigned int)f2bf(o1) << 16);
                p.y = (unsigned int)f2bf(o2) | ((unsigned int)f2bf(o3) << 16);
                *(uint2*)(y + (size_t)node * FDIM + jq) = p;
            }
        }
    } else {
        __syncthreads();
#pragma unroll
        for (int i = 0; i < 4; i++) {
            float4 o;
            o.x = fmaxf(a[i][0], 0.f); o.y = fmaxf(a[i][1], 0.f);
            o.z = fmaxf(a[i][2], 0.f); o.w = fmaxf(a[i][3], 0.f);
            *(float4*)(&sh[(r0 + i) * HPAD + jq]) = o;
        }
        __syncthreads();
        for (int i = tid; i < 64 * 10; i += 256) {
            int nl = i / 10, cc = i % 10;
            int node = base + nl;
            if (node < n_nodes) {
                float s = sbl[cc];
#pragma unroll
                for (int k0 = 0; k0 < FDIM; k0 += 4) {
                    float4 hv = *(float4*)(&sh[nl * HPAD + k0]);
                    s += hv.x * sWl[(k0 + 0) * 10 + cc] + hv.y * sWl[(k0 + 1) * 10 + cc]
                       + hv.z * sWl[(k0 + 2) * 10 + cc] + hv.w * sWl[(k0 + 3) * 10 + cc];
                }
                out[(size_t)node * 10 + cc] = s;
            }
        }
    }
}

extern "C" void kernel_launch(void* const* d_in, const int* in_sizes, int n_in,
                              void* d_out, int out_size, void* d_ws, size_t ws_size,
                              hipStream_t stream) {
    const float* features = (const float*)d_in[0];
    const int* edges = (const int*)d_in[1];
    int n_nodes = in_sizes[0] / FDIM;          // 50000
    int n_edges = in_sizes[1] / 2;             // 800000
    const int* src = edges;
    const int* dst = edges + n_edges;

    int nbuck = (n_nodes + BNODES - 1) / BNODES;     // 782
    int nchunks = (n_edges + CHUNK - 1) / CHUNK;     // 391

    // workspace: bucket_total_pad | cursor_pad | bucket_start | row_ptr | packed | src_sorted | bf16 bufs
    int* bucket_total_pad = (int*)d_ws;                              // nbuck*16
    int* cursor_pad = bucket_total_pad + (size_t)nbuck * 16;         // nbuck*16
    int* bucket_start = cursor_pad + (size_t)nbuck * 16;             // nbuck+1
    int* row_ptr = bucket_start + nbuck + 1;                         // n_nodes+1
    unsigned int* packed = (unsigned int*)(row_ptr + n_nodes + 1);   // n_edges
    int* src_sorted = (int*)(packed + n_edges);                      // n_edges
    size_t int_elems = 32 * (size_t)nbuck + (size_t)nbuck + 1
                       + (size_t)n_nodes + 1 + 2 * (size_t)n_edges;
    int_elems = (int_elems + 3) & ~(size_t)3;
    size_t buf_elems = (size_t)n_nodes * FDIM;
    unsigned short* hb  = (unsigned short*)((int*)d_ws + int_elems);
    unsigned short* xb0 = hb + buf_elems;
    unsigned short* yA  = xb0 + buf_elems;
    unsigned short* yB  = yA + buf_elems;

    dim3 bs(256);
    dim3 gs_cast(((int)(buf_elems / 4) + 255) / 256);
    dim3 gs_gather((n_nodes + 31) / 32);   // 1563
    dim3 gs_tile((n_nodes + 63) / 64);     // 782

    // --- zero padded bucket totals; cast features to bf16 ---
    hipMemsetAsync(bucket_total_pad, 0, (size_t)nbuck * 16 * sizeof(int), stream);
    cast_bf16<<<gs_cast, bs, 0, stream>>>(features, xb0, (int)(buf_elems / 4));

    // --- build node-grouped CSR (4 kernels) ---
    bucket_hist_total<<<nchunks, 256, 0, stream>>>(dst, bucket_total_pad, n_edges, nbuck);
    scan_buckets<<<1, 1024, 0, stream>>>(bucket_total_pad, bucket_start, cursor_pad,
                                         row_ptr, nbuck, n_nodes, n_edges);
    bucket_fill_atomic<<<nchunks, 256, 0, stream>>>(src, dst, cursor_pad, packed, n_edges);
    sort_bucket<<<nbuck, 256, 0, stream>>>(packed, bucket_start, src_sorted, row_ptr, n_nodes);

    // --- 3 GIN convs, split gather/MLP (last MLP fuses the final linear) ---
    const float* Wl = (const float*)d_in[14];
    const float* bl = (const float*)d_in[15];
    const unsigned short* x_cur = xb0;
    unsigned short* outs[3] = {yA, yB, yA};
    for (int conv = 0; conv < 3; conv++) {
        const float* W1 = (const float*)d_in[2 + 4 * conv];
        const float* b1 = (const float*)d_in[3 + 4 * conv];
        const float* W2 = (const float*)d_in[4 + 4 * conv];
        const float* b2 = (const float*)d_in[5 + 4 * conv];
        int fin = (conv == 2) ? 1 : 0;

        gather_bf16<<<gs_gather, bs, 0, stream>>>(x_cur, row_ptr, src_sorted, hb, n_nodes);
        mlp_tile<<<gs_tile, bs, 0, stream>>>(hb, W1, b1, W2, b2, Wl, bl,
                                             outs[conv], (float*)d_out, n_nodes, fin);
        x_cur = outs[conv];
    }
}

// Round 11
// 261.407 us; speedup vs baseline: 1.1784x; 1.0835x over previous
//
#include <hip/hip_runtime.h>
#include <hip/hip_bf16.h>

#define FDIM 64
#define BNODES 64          // nodes per bucket (dst >> 6)
#define CHUNK 2048         // edges per partition chunk (391 chunks)
#define HPADB 72           // padded bf16 LDS row (144B: 16B-aligned, 36-dword stride)
#define GCAP 768           // staged edge-index capacity per gather block (16 nodes)

__device__ __forceinline__ unsigned short f2bf(float f) {
    unsigned int u = __float_as_uint(f);
    unsigned int r = (u + 0x7fffu + ((u >> 16) & 1u)) >> 16;   // RNE
    return (unsigned short)r;
}
__device__ __forceinline__ float bflo(unsigned int p) { return __uint_as_float(p << 16); }
__device__ __forceinline__ float bfhi(unsigned int p) { return __uint_as_float(p & 0xffff0000u); }

// ---- cast fp32 -> bf16 (features), 4 elems/thread ----
__global__ __launch_bounds__(256) void cast_bf16(const float* __restrict__ x,
                                                 unsigned short* __restrict__ xb, int n4) {
    int i = blockIdx.x * blockDim.x + threadIdx.x;
    if (i < n4) {
        float4 v = ((const float4*)x)[i];
        uint2 o;
        o.x = (unsigned int)f2bf(v.x) | ((unsigned int)f2bf(v.y) << 16);
        o.y = (unsigned int)f2bf(v.z) | ((unsigned int)f2bf(v.w) << 16);
        ((uint2*)xb)[i] = o;
    }
}

// ---- pass 1: per-chunk bucket histogram (LDS) ----
__global__ __launch_bounds__(256) void bucket_hist(const int* __restrict__ dst,
                                                   int* __restrict__ hist,
                                                   int n_edges, int nbuck) {
    __shared__ int lh[1024];
    int chunk = blockIdx.x;
    for (int i = threadIdx.x; i < nbuck; i += 256) lh[i] = 0;
    __syncthreads();
    int beg = chunk * CHUNK;
    int end = min(beg + CHUNK, n_edges);
    for (int e = beg + threadIdx.x; e < end; e += 256)
        atomicAdd(&lh[dst[e] >> 6], 1);
    __syncthreads();
    for (int i = threadIdx.x; i < nbuck; i += 256)
        hist[(size_t)chunk * nbuck + i] = lh[i];
}

// ---- pass 2a: per-bucket exclusive scan over chunks (nchunks <= 512) ----
__global__ __launch_bounds__(512) void scan_chunks(const int* __restrict__ hist,
                                                   int* __restrict__ chunk_off,
                                                   int* __restrict__ bucket_total,
                                                   int nchunks, int nbuck) {
    __shared__ int s[512];
    int b = blockIdx.x;
    int t = threadIdx.x;
    int v = (t < nchunks) ? hist[(size_t)t * nbuck + b] : 0;
    s[t] = v;
    __syncthreads();
    for (int off = 1; off < 512; off <<= 1) {
        int u = (t >= off) ? s[t - off] : 0;
        __syncthreads();
        s[t] += u;
        __syncthreads();
    }
    if (t < nchunks) chunk_off[(size_t)t * nbuck + b] = s[t] - v;  // exclusive
    if (t == 511) bucket_total[b] = s[511];
}

// ---- pass 2b: exclusive scan of bucket totals ----
__global__ __launch_bounds__(1024) void scan_buckets(const int* __restrict__ bucket_total,
                                                     int* __restrict__ bucket_start,
                                                     int* __restrict__ row_ptr,
                                                     int nbuck, int n_nodes, int n_edges) {
    __shared__ int s[1024];
    int t = threadIdx.x;
    int v = (t < nbuck) ? bucket_total[t] : 0;
    s[t] = v;
    __syncthreads();
    for (int off = 1; off < 1024; off <<= 1) {
        int u = (t >= off) ? s[t - off] : 0;
        __syncthreads();
        s[t] += u;
        __syncthreads();
    }
    if (t < nbuck) bucket_start[t] = s[t] - v;
    if (t == 0) { bucket_start[nbuck] = n_edges; row_ptr[n_nodes] = n_edges; }
}

// ---- pass 3: fill packed edges, (chunk,bucket)-contiguous runs ----
__global__ __launch_bounds__(256) void bucket_fill(const int* __restrict__ src,
                                                   const int* __restrict__ dst,
                                                   const int* __restrict__ bucket_start,
                                                   const int* __restrict__ chunk_off,
                                                   unsigned int* __restrict__ packed,
                                                   int n_edges, int nbuck) {
    __shared__ int cur[1024];
    int chunk = blockIdx.x;
    for (int i = threadIdx.x; i < nbuck; i += 256)
        cur[i] = bucket_start[i] + chunk_off[(size_t)chunk * nbuck + i];
    __syncthreads();
    int beg = chunk * CHUNK;
    int end = min(beg + CHUNK, n_edges);
    for (int e = beg + threadIdx.x; e < end; e += 256) {
        int d = dst[e];
        int b = d >> 6;
        int pos = atomicAdd(&cur[b], 1);
        packed[pos] = (unsigned int)src[e] | ((unsigned int)(d & 63) << 16);
    }
}

// ---- pass 4: within-bucket sort to node granularity + row_ptr emit ----
__global__ __launch_bounds__(256) void sort_bucket(const unsigned int* __restrict__ packed,
                                                   const int* __restrict__ bucket_start,
                                                   int* __restrict__ src_sorted,
                                                   int* __restrict__ row_ptr, int n_nodes) {
    __shared__ int cnt[BNODES];
    __shared__ int cur[BNODES];
    int b = blockIdx.x;
    int beg = bucket_start[b], end = bucket_start[b + 1];
    if (threadIdx.x < BNODES) cnt[threadIdx.x] = 0;
    __syncthreads();
    for (int e = beg + threadIdx.x; e < end; e += 256)
        atomicAdd(&cnt[packed[e] >> 16], 1);
    __syncthreads();
    if (threadIdx.x < 64) {       // one wave: shfl inclusive scan over 64 degrees
        int v = cnt[threadIdx.x];
        int inc = v;
#pragma unroll
        for (int off = 1; off < 64; off <<= 1) {
            int u = __shfl_up(inc, off, 64);
            if (threadIdx.x >= off) inc += u;
        }
        cur[threadIdx.x] = beg + inc - v;     // exclusive
        int node = b * BNODES + threadIdx.x;
        if (node < n_nodes) row_ptr[node] = beg + inc - v;
    }
    __syncthreads();
    for (int e = beg + threadIdx.x; e < end; e += 256) {
        unsigned int p = packed[e];
        int pos = atomicAdd(&cur[p >> 16], 1);
        src_sorted[pos] = (int)(p & 0xFFFFu);
    }
}

// gather (bf16 in/out, fp32 accum): 16 nodes/block, 16 threads/node, uint2 lanes.
__global__ __launch_bounds__(256) void gather_bf16(const unsigned short* __restrict__ xb,
                                                   const int* __restrict__ row_ptr,
                                                   const int* __restrict__ src_sorted,
                                                   unsigned short* __restrict__ hb,
                                                   int n_nodes) {
    __shared__ int sidx[GCAP];
    int base = blockIdx.x * 16;
    int ebeg = row_ptr[base];
    int eend = row_ptr[min(base + 16, n_nodes)];
    int total = eend - ebeg;
    int cnt = min(total, GCAP);
    for (int i = threadIdx.x; i < cnt; i += 256) sidx[i] = src_sorted[ebeg + i];
    __syncthreads();

    int t = threadIdx.x;
    int node = base + (t >> 4);
    if (node >= n_nodes) return;
    int c = (t & 15) * 4;
    int dbeg = row_ptr[node] - ebeg;
    int dend = row_ptr[node + 1] - ebeg;

    float4 acc;
    {
        uint2 v = *(const uint2*)(xb + (size_t)node * FDIM + c);
        acc.x = bflo(v.x); acc.y = bfhi(v.x);
        acc.z = bflo(v.y); acc.w = bfhi(v.y);
    }

    if (total <= GCAP) {          // fast path
        int e = dbeg;
        for (; e + 7 < dend; e += 8) {
            int s[8];
#pragma unroll
            for (int j = 0; j < 8; j++) s[j] = sidx[e + j];
            uint2 v[8];
#pragma unroll
            for (int j = 0; j < 8; j++) v[j] = *(const uint2*)(xb + (size_t)s[j] * FDIM + c);
#pragma unroll
            for (int j = 0; j < 8; j++) {
                acc.x += bflo(v[j].x); acc.y += bfhi(v[j].x);
                acc.z += bflo(v[j].y); acc.w += bfhi(v[j].y);
            }
        }
        if (e + 3 < dend) {
            int s[4];
#pragma unroll
            for (int j = 0; j < 4; j++) s[j] = sidx[e + j];
            uint2 v[4];
#pragma unroll
            for (int j = 0; j < 4; j++) v[j] = *(const uint2*)(xb + (size_t)s[j] * FDIM + c);
#pragma unroll
            for (int j = 0; j < 4; j++) {
                acc.x += bflo(v[j].x); acc.y += bfhi(v[j].x);
                acc.z += bflo(v[j].y); acc.w += bfhi(v[j].y);
            }
            e += 4;
        }
        for (; e < dend; e++) {
            uint2 v = *(const uint2*)(xb + (size_t)sidx[e] * FDIM + c);
            acc.x += bflo(v.x); acc.y += bfhi(v.x);
            acc.z += bflo(v.y); acc.w += bfhi(v.y);
        }
    } else {                      // overflow fallback
        for (int e = dbeg; e < dend; e++) {
            int si = (e < cnt) ? sidx[e] : src_sorted[ebeg + e];
            uint2 v = *(const uint2*)(xb + (size_t)si * FDIM + c);
            acc.x += bflo(v.x); acc.y += bfhi(v.x);
            acc.z += bflo(v.y); acc.w += bfhi(v.y);
        }
    }

    uint2 p;
    p.x = (unsigned int)f2bf(acc.x) | ((unsigned int)f2bf(acc.y) << 16);
    p.y = (unsigned int)f2bf(acc.z) | ((unsigned int)f2bf(acc.w) << 16);
    *(uint2*)(hb + (size_t)node * FDIM + c) = p;
}

// MLP over a 64-node tile, 4 nodes/thread; fp32 math, bf16 LDS storage
// (W1/W2/h/g all bf16 in LDS -> 28.7KB -> 5 blocks/CU).
__global__ __launch_bounds__(256) void mlp_tile(const unsigned short* __restrict__ xb,
        const float* __restrict__ W1, const float* __restrict__ b1,
        const float* __restrict__ W2, const float* __restrict__ b2,
        const float* __restrict__ Wl, const float* __restrict__ bl,
        unsigned short* __restrict__ y, float* __restrict__ out,
        int n_nodes, int do_final) {
    __shared__ unsigned short sW1b[FDIM * FDIM];
    __shared__ unsigned short sW2b[FDIM * FDIM];
    __shared__ unsigned short shb[64 * HPADB];
    __shared__ float sb1[FDIM], sb2[FDIM];
    __shared__ float sWl[FDIM * 10];
    __shared__ float sbl[16];

    int tid = threadIdx.x;
    int base = blockIdx.x * 64;

    // stage weights fp32 -> bf16 LDS: 1024 float4, 4 per thread
    {
        const float4* W14 = (const float4*)W1;
        const float4* W24 = (const float4*)W2;
#pragma unroll
        for (int k = 0; k < 4; k++) {
            int idx = tid + k * 256;
            float4 v1 = W14[idx];
            float4 v2 = W24[idx];
            uint2 p1, p2;
            p1.x = (unsigned int)f2bf(v1.x) | ((unsigned int)f2bf(v1.y) << 16);
            p1.y = (unsigned int)f2bf(v1.z) | ((unsigned int)f2bf(v1.w) << 16);
            p2.x = (unsigned int)f2bf(v2.x) | ((unsigned int)f2bf(v2.y) << 16);
            p2.y = (unsigned int)f2bf(v2.z) | ((unsigned int)f2bf(v2.w) << 16);
            *(uint2*)(&sW1b[idx * 4]) = p1;
            *(uint2*)(&sW2b[idx * 4]) = p2;
        }
    }
    if (tid < FDIM) { sb1[tid] = b1[tid]; sb2[tid] = b2[tid]; }
    if (do_final) {
        for (int i = tid; i < FDIM * 10; i += 256) sWl[i] = Wl[i];
        if (tid < 10) sbl[tid] = bl[tid];
    }
    // stage h tile (already bf16): 64 rows x 8 uint4, 2 per thread, coalesced
    {
#pragma unroll
        for (int k = 0; k < 2; k++) {
            int idx = tid + k * 256;
            int r = idx >> 3, q = idx & 7;
            int node = base + r;
            uint4 v = make_uint4(0u, 0u, 0u, 0u);
            if (node < n_nodes) v = *(const uint4*)(xb + (size_t)node * FDIM + q * 8);
            *(uint4*)(&shb[r * HPADB + q * 8]) = v;
        }
    }
    __syncthreads();

    int ng = tid >> 4;
    int jq = (tid & 15) * 4;
    int r0 = ng * 4;

    float a[4][4];
    // ---- layer 1 ----
#pragma unroll
    for (int i = 0; i < 4; i++) {
        a[i][0] = sb1[jq]; a[i][1] = sb1[jq + 1];
        a[i][2] = sb1[jq + 2]; a[i][3] = sb1[jq + 3];
    }
#pragma unroll
    for (int k0 = 0; k0 < FDIM; k0 += 4) {
        float4 w[4];
#pragma unroll
        for (int kk = 0; kk < 4; kk++) {
            uint2 wp = *(uint2*)(&sW1b[(k0 + kk) * FDIM + jq]);
            w[kk].x = bflo(wp.x); w[kk].y = bfhi(wp.x);
            w[kk].z = bflo(wp.y); w[kk].w = bfhi(wp.y);
        }
#pragma unroll
        for (int i = 0; i < 4; i++) {
            uint2 hp = *(uint2*)(&shb[(r0 + i) * HPADB + k0]);
            float hx = bflo(hp.x), hy = bfhi(hp.x), hz = bflo(hp.y), hw = bfhi(hp.y);
            a[i][0] += hx * w[0].x + hy * w[1].x + hz * w[2].x + hw * w[3].x;
            a[i][1] += hx * w[0].y + hy * w[1].y + hz * w[2].y + hw * w[3].y;
            a[i][2] += hx * w[0].z + hy * w[1].z + hz * w[2].z + hw * w[3].z;
            a[i][3] += hx * w[0].w + hy * w[1].w + hz * w[2].w + hw * w[3].w;
        }
    }
    __syncthreads();   // all h reads done
#pragma unroll
    for (int i = 0; i < 4; i++) {
        float g0 = fmaxf(a[i][0], 0.f), g1 = fmaxf(a[i][1], 0.f);
        float g2 = fmaxf(a[i][2], 0.f), g3 = fmaxf(a[i][3], 0.f);
        uint2 gp;
        gp.x = (unsigned int)f2bf(g0) | ((unsigned int)f2bf(g1) << 16);
        gp.y = (unsigned int)f2bf(g2) | ((unsigned int)f2bf(g3) << 16);
        *(uint2*)(&shb[(r0 + i) * HPADB + jq]) = gp;
    }
    __syncthreads();

    // ---- layer 2 ----
#pragma unroll
    for (int i = 0; i < 4; i++) {
        a[i][0] = sb2[jq]; a[i][1] = sb2[jq + 1];
        a[i][2] = sb2[jq + 2]; a[i][3] = sb2[jq + 3];
    }
#pragma unroll
    for (int k0 = 0; k0 < FDIM; k0 += 4) {
        float4 w[4];
#pragma unroll
        for (int kk = 0; kk < 4; kk++) {
            uint2 wp = *(uint2*)(&sW2b[(k0 + kk) * FDIM + jq]);
            w[kk].x = bflo(wp.x); w[kk].y = bfhi(wp.x);
            w[kk].z = bflo(wp.y); w[kk].w = bfhi(wp.y);
        }
#pragma unroll
        for (int i = 0; i < 4; i++) {
            uint2 hp = *(uint2*)(&shb[(r0 + i) * HPADB + k0]);
            float hx = bflo(hp.x), hy = bfhi(hp.x), hz = bflo(hp.y), hw = bfhi(hp.y);
            a[i][0] += hx * w[0].x + hy * w[1].x + hz * w[2].x + hw * w[3].x;
            a[i][1] += hx * w[0].y + hy * w[1].y + hz * w[2].y + hw * w[3].y;
            a[i][2] += hx * w[0].z + hy * w[1].z + hz * w[2].z + hw * w[3].z;
            a[i][3] += hx * w[0].w + hy * w[1].w + hz * w[2].w + hw * w[3].w;
        }
    }

    if (!do_final) {
#pragma unroll
        for (int i = 0; i < 4; i++) {
            int node = base + r0 + i;
            if (node < n_nodes) {
                float o0 = fmaxf(a[i][0], 0.f), o1 = fmaxf(a[i][1], 0.f);
                float o2 = fmaxf(a[i][2], 0.f), o3 = fmaxf(a[i][3], 0.f);
                uint2 p;
                p.x = (unsigned int)f2bf(o0) | ((unsigned int)f2bf(o1) << 16);
                p.y = (unsigned int)f2bf(o2) | ((unsigned int)f2bf(o3) << 16);
                *(uint2*)(y + (size_t)node * FDIM + jq) = p;
            }
        }
    } else {
        __syncthreads();
#pragma unroll
        for (int i = 0; i < 4; i++) {
            float o0 = fmaxf(a[i][0], 0.f), o1 = fmaxf(a[i][1], 0.f);
            float o2 = fmaxf(a[i][2], 0.f), o3 = fmaxf(a[i][3], 0.f);
            uint2 p;
            p.x = (unsigned int)f2bf(o0) | ((unsigned int)f2bf(o1) << 16);
            p.y = (unsigned int)f2bf(o2) | ((unsigned int)f2bf(o3) << 16);
            *(uint2*)(&shb[(r0 + i) * HPADB + jq]) = p;
        }
        __syncthreads();
        for (int i = tid; i < 64 * 10; i += 256) {
            int nl = i / 10, cc = i % 10;
            int node = base + nl;
            if (node < n_nodes) {
                float s = sbl[cc];
#pragma unroll
                for (int k0 = 0; k0 < FDIM; k0 += 4) {
                    uint2 hp = *(uint2*)(&shb[nl * HPADB + k0]);
                    s += bflo(hp.x) * sWl[(k0 + 0) * 10 + cc] + bfhi(hp.x) * sWl[(k0 + 1) * 10 + cc]
                       + bflo(hp.y) * sWl[(k0 + 2) * 10 + cc] + bfhi(hp.y) * sWl[(k0 + 3) * 10 + cc];
                }
                out[(size_t)node * 10 + cc] = s;
            }
        }
    }
}

extern "C" void kernel_launch(void* const* d_in, const int* in_sizes, int n_in,
                              void* d_out, int out_size, void* d_ws, size_t ws_size,
                              hipStream_t stream) {
    const float* features = (const float*)d_in[0];
    const int* edges = (const int*)d_in[1];
    int n_nodes = in_sizes[0] / FDIM;          // 50000
    int n_edges = in_sizes[1] / 2;             // 800000
    const int* src = edges;
    const int* dst = edges + n_edges;

    int nbuck = (n_nodes + BNODES - 1) / BNODES;     // 782
    int nchunks = (n_edges + CHUNK - 1) / CHUNK;     // 391

    // workspace: hist | chunk_off | bucket_total | bucket_start | row_ptr | packed | src_sorted | bf16 bufs
    int* hist = (int*)d_ws;
    int* chunk_off = hist + (size_t)nchunks * nbuck;
    int* bucket_total = chunk_off + (size_t)nchunks * nbuck;
    int* bucket_start = bucket_total + nbuck;
    int* row_ptr = bucket_start + nbuck + 1;
    unsigned int* packed = (unsigned int*)(row_ptr + n_nodes + 1);
    int* src_sorted = (int*)(packed + n_edges);
    size_t int_elems = 2 * (size_t)nchunks * nbuck + 2 * (size_t)nbuck + 2
                       + (size_t)n_nodes + 2 * (size_t)n_edges;
    int_elems = (int_elems + 3) & ~(size_t)3;
    size_t buf_elems = (size_t)n_nodes * FDIM;
    unsigned short* hb  = (unsigned short*)((int*)d_ws + int_elems);
    unsigned short* xb0 = hb + buf_elems;
    unsigned short* yA  = xb0 + buf_elems;
    unsigned short* yB  = yA + buf_elems;

    dim3 bs(256);
    dim3 gs_cast(((int)(buf_elems / 4) + 255) / 256);
    dim3 gs_gather((n_nodes + 15) / 16);   // 3125
    dim3 gs_tile((n_nodes + 63) / 64);     // 782

    // --- cast features to bf16 ---
    cast_bf16<<<gs_cast, bs, 0, stream>>>(features, xb0, (int)(buf_elems / 4));

    // --- build node-grouped CSR via 2-pass bucket sort (deterministic fill) ---
    bucket_hist<<<nchunks, 256, 0, stream>>>(dst, hist, n_edges, nbuck);
    scan_chunks<<<nbuck, 512, 0, stream>>>(hist, chunk_off, bucket_total, nchunks, nbuck);
    scan_buckets<<<1, 1024, 0, stream>>>(bucket_total, bucket_start, row_ptr, nbuck, n_nodes, n_edges);
    bucket_fill<<<nchunks, 256, 0, stream>>>(src, dst, bucket_start, chunk_off, packed, n_edges, nbuck);
    sort_bucket<<<nbuck, 256, 0, stream>>>(packed, bucket_start, src_sorted, row_ptr, n_nodes);

    // --- 3 GIN convs, split gather/MLP (last MLP fuses the final linear) ---
    const float* Wl = (const float*)d_in[14];
    const float* bl = (const float*)d_in[15];
    const unsigned short* x_cur = xb0;
    unsigned short* outs[3] = {yA, yB, yA};
    for (int conv = 0; conv < 3; conv++) {
        const float* W1 = (const float*)d_in[2 + 4 * conv];
        const float* b1 = (const float*)d_in[3 + 4 * conv];
        const float* W2 = (const float*)d_in[4 + 4 * conv];
        const float* b2 = (const float*)d_in[5 + 4 * conv];
        int fin = (conv == 2) ? 1 : 0;

        gather_bf16<<<gs_gather, bs, 0, stream>>>(x_cur, row_ptr, src_sorted, hb, n_nodes);
        mlp_tile<<<gs_tile, bs, 0, stream>>>(hb, W1, b1, W2, b2, Wl, bl,
                                             outs[conv], (float*)d_out, n_nodes, fin);
        x_cur = outs[conv];
    }
}

// Round 12
// 223.734 us; speedup vs baseline: 1.3769x; 1.1684x over previous
//
#include <hip/hip_runtime.h>
#include <hip/hip_bf16.h>

#define FDIM 64
#define BNODES 64          // nodes per bucket (dst >> 6)
#define CHUNK 8192         // edges per partition chunk (98 chunks)
#define HP 72              // padded LDS row stride in shorts (144B; rows 8 apart share banks = 2-way, free)
#define GCAP 768           // staged edge-index capacity per gather block (16 nodes)

typedef short bf16x8 __attribute__((ext_vector_type(8)));
typedef float f32x4 __attribute__((ext_vector_type(4)));

__device__ __forceinline__ unsigned short f2bf(float f) {
    unsigned int u = __float_as_uint(f);
    unsigned int r = (u + 0x7fffu + ((u >> 16) & 1u)) >> 16;   // RNE
    return (unsigned short)r;
}
__device__ __forceinline__ float bflo(unsigned int p) { return __uint_as_float(p << 16); }
__device__ __forceinline__ float bfhi(unsigned int p) { return __uint_as_float(p & 0xffff0000u); }

// ---- cast fp32 -> bf16 (features), 4 elems/thread ----
__global__ __launch_bounds__(256) void cast_bf16(const float* __restrict__ x,
                                                 unsigned short* __restrict__ xb, int n4) {
    int i = blockIdx.x * blockDim.x + threadIdx.x;
    if (i < n4) {
        float4 v = ((const float4*)x)[i];
        uint2 o;
        o.x = (unsigned int)f2bf(v.x) | ((unsigned int)f2bf(v.y) << 16);
        o.y = (unsigned int)f2bf(v.z) | ((unsigned int)f2bf(v.w) << 16);
        ((uint2*)xb)[i] = o;
    }
}

// ---- pass 1: per-chunk bucket histogram (LDS) ----
__global__ __launch_bounds__(256) void bucket_hist(const int* __restrict__ dst,
                                                   int* __restrict__ hist,
                                                   int n_edges, int nbuck) {
    __shared__ int lh[1024];
    int chunk = blockIdx.x;
    for (int i = threadIdx.x; i < nbuck; i += 256) lh[i] = 0;
    __syncthreads();
    int beg = chunk * CHUNK;
    int end = min(beg + CHUNK, n_edges);
    for (int e = beg + threadIdx.x; e < end; e += 256)
        atomicAdd(&lh[dst[e] >> 6], 1);
    __syncthreads();
    for (int i = threadIdx.x; i < nbuck; i += 256)
        hist[(size_t)chunk * nbuck + i] = lh[i];
}

// ---- pass 2a: per-bucket exclusive scan over chunks (nchunks <= 256) ----
__global__ __launch_bounds__(256) void scan_chunks(const int* __restrict__ hist,
                                                   int* __restrict__ chunk_off,
                                                   int* __restrict__ bucket_total,
                                                   int nchunks, int nbuck) {
    __shared__ int s[256];
    int b = blockIdx.x;
    int t = threadIdx.x;
    int v = (t < nchunks) ? hist[(size_t)t * nbuck + b] : 0;
    s[t] = v;
    __syncthreads();
    for (int off = 1; off < 256; off <<= 1) {
        int u = (t >= off) ? s[t - off] : 0;
        __syncthreads();
        s[t] += u;
        __syncthreads();
    }
    if (t < nchunks) chunk_off[(size_t)t * nbuck + b] = s[t] - v;  // exclusive
    if (t == 255) bucket_total[b] = s[255];
}

// ---- pass 2b: exclusive scan of bucket totals ----
__global__ __launch_bounds__(1024) void scan_buckets(const int* __restrict__ bucket_total,
                                                     int* __restrict__ bucket_start,
                                                     int* __restrict__ row_ptr,
                                                     int nbuck, int n_nodes, int n_edges) {
    __shared__ int s[1024];
    int t = threadIdx.x;
    int v = (t < nbuck) ? bucket_total[t] : 0;
    s[t] = v;
    __syncthreads();
    for (int off = 1; off < 1024; off <<= 1) {
        int u = (t >= off) ? s[t - off] : 0;
        __syncthreads();
        s[t] += u;
        __syncthreads();
    }
    if (t < nbuck) bucket_start[t] = s[t] - v;
    if (t == 0) { bucket_start[nbuck] = n_edges; row_ptr[n_nodes] = n_edges; }
}

// ---- pass 3: fill packed edges, (chunk,bucket)-contiguous runs ----
__global__ __launch_bounds__(256) void bucket_fill(const int* __restrict__ src,
                                                   const int* __restrict__ dst,
                                                   const int* __restrict__ bucket_start,
                                                   const int* __restrict__ chunk_off,
                                                   unsigned int* __restrict__ packed,
                                                   int n_edges, int nbuck) {
    __shared__ int cur[1024];
    int chunk = blockIdx.x;
    for (int i = threadIdx.x; i < nbuck; i += 256)
        cur[i] = bucket_start[i] + chunk_off[(size_t)chunk * nbuck + i];
    __syncthreads();
    int beg = chunk * CHUNK;
    int end = min(beg + CHUNK, n_edges);
    for (int e = beg + threadIdx.x; e < end; e += 256) {
        int d = dst[e];
        int b = d >> 6;
        int pos = atomicAdd(&cur[b], 1);
        packed[pos] = (unsigned int)src[e] | ((unsigned int)(d & 63) << 16);
    }
}

// ---- pass 4: within-bucket sort to node granularity + row_ptr emit ----
__global__ __launch_bounds__(256) void sort_bucket(const unsigned int* __restrict__ packed,
                                                   const int* __restrict__ bucket_start,
                                                   int* __restrict__ src_sorted,
                                                   int* __restrict__ row_ptr, int n_nodes) {
    __shared__ int cnt[BNODES];
    __shared__ int cur[BNODES];
    int b = blockIdx.x;
    int beg = bucket_start[b], end = bucket_start[b + 1];
    if (threadIdx.x < BNODES) cnt[threadIdx.x] = 0;
    __syncthreads();
    for (int e = beg + threadIdx.x; e < end; e += 256)
        atomicAdd(&cnt[packed[e] >> 16], 1);
    __syncthreads();
    if (threadIdx.x < 64) {       // one wave: shfl inclusive scan over 64 degrees
        int v = cnt[threadIdx.x];
        int inc = v;
#pragma unroll
        for (int off = 1; off < 64; off <<= 1) {
            int u = __shfl_up(inc, off, 64);
            if (threadIdx.x >= off) inc += u;
        }
        cur[threadIdx.x] = beg + inc - v;     // exclusive
        int node = b * BNODES + threadIdx.x;
        if (node < n_nodes) row_ptr[node] = beg + inc - v;
    }
    __syncthreads();
    for (int e = beg + threadIdx.x; e < end; e += 256) {
        unsigned int p = packed[e];
        int pos = atomicAdd(&cur[p >> 16], 1);
        src_sorted[pos] = (int)(p & 0xFFFFu);
    }
}

// gather (bf16 in/out, fp32 accum): 16 nodes/block, 16 threads/node, uint2 lanes.
__global__ __launch_bounds__(256) void gather_bf16(const unsigned short* __restrict__ xb,
                                                   const int* __restrict__ row_ptr,
                                                   const int* __restrict__ src_sorted,
                                                   unsigned short* __restrict__ hb,
                                                   int n_nodes) {
    __shared__ int sidx[GCAP];
    int base = blockIdx.x * 16;
    int ebeg = row_ptr[base];
    int eend = row_ptr[min(base + 16, n_nodes)];
    int total = eend - ebeg;
    int cnt = min(total, GCAP);
    for (int i = threadIdx.x; i < cnt; i += 256) sidx[i] = src_sorted[ebeg + i];
    __syncthreads();

    int t = threadIdx.x;
    int node = base + (t >> 4);
    if (node >= n_nodes) return;
    int c = (t & 15) * 4;
    int dbeg = row_ptr[node] - ebeg;
    int dend = row_ptr[node + 1] - ebeg;

    float4 acc;
    {
        uint2 v = *(const uint2*)(xb + (size_t)node * FDIM + c);
        acc.x = bflo(v.x); acc.y = bfhi(v.x);
        acc.z = bflo(v.y); acc.w = bfhi(v.y);
    }

    if (total <= GCAP) {          // fast path
        int e = dbeg;
        for (; e + 7 < dend; e += 8) {
            int s[8];
#pragma unroll
            for (int j = 0; j < 8; j++) s[j] = sidx[e + j];
            uint2 v[8];
#pragma unroll
            for (int j = 0; j < 8; j++) v[j] = *(const uint2*)(xb + (size_t)s[j] * FDIM + c);
#pragma unroll
            for (int j = 0; j < 8; j++) {
                acc.x += bflo(v[j].x); acc.y += bfhi(v[j].x);
                acc.z += bflo(v[j].y); acc.w += bfhi(v[j].y);
            }
        }
        if (e + 3 < dend) {
            int s[4];
#pragma unroll
            for (int j = 0; j < 4; j++) s[j] = sidx[e + j];
            uint2 v[4];
#pragma unroll
            for (int j = 0; j < 4; j++) v[j] = *(const uint2*)(xb + (size_t)s[j] * FDIM + c);
#pragma unroll
            for (int j = 0; j < 4; j++) {
                acc.x += bflo(v[j].x); acc.y += bfhi(v[j].x);
                acc.z += bflo(v[j].y); acc.w += bfhi(v[j].y);
            }
            e += 4;
        }
        for (; e < dend; e++) {
            uint2 v = *(const uint2*)(xb + (size_t)sidx[e] * FDIM + c);
            acc.x += bflo(v.x); acc.y += bfhi(v.x);
            acc.z += bflo(v.y); acc.w += bfhi(v.y);
        }
    } else {                      // overflow fallback
        for (int e = dbeg; e < dend; e++) {
            int si = (e < cnt) ? sidx[e] : src_sorted[ebeg + e];
            uint2 v = *(const uint2*)(xb + (size_t)si * FDIM + c);
            acc.x += bflo(v.x); acc.y += bfhi(v.x);
            acc.z += bflo(v.y); acc.w += bfhi(v.y);
        }
    }

    uint2 p;
    p.x = (unsigned int)f2bf(acc.x) | ((unsigned int)f2bf(acc.y) << 16);
    p.y = (unsigned int)f2bf(acc.z) | ((unsigned int)f2bf(acc.w) << 16);
    *(uint2*)(hb + (size_t)node * FDIM + c) = p;
}

// ---- MFMA MLP over a 64-node tile ----
// 4 waves; wave w owns node rows [w*16, w*16+16). Per layer: 4 N-subtiles x 2 K-chunks
// = 8 v_mfma_f32_16x16x32_bf16 per wave. A-frag: A[m=lane&15][k=quad*8+j] (b128 from
// row-major tile). B-frag: B[k][n=lane&15] -> W stored TRANSPOSED in LDS ([n][k]).
// C/D: col=lane&15, row=quad*4+reg. G and O written in-place over the H tile
// (each wave touches only its own rows -> no inter-layer barrier).
__global__ __launch_bounds__(256) void mlp_mfma(const unsigned short* __restrict__ xb,
        const float* __restrict__ W1, const float* __restrict__ b1,
        const float* __restrict__ W2, const float* __restrict__ b2,
        const float* __restrict__ Wl, const float* __restrict__ bl,
        unsigned short* __restrict__ y, float* __restrict__ out,
        int n_nodes, int do_final) {
    __shared__ unsigned short sH[64 * HP];      // H -> G -> O (bf16)
    __shared__ unsigned short sW1t[64 * HP];    // W1^T [n][k] bf16
    __shared__ unsigned short sW2t[64 * HP];    // W2^T [n][k] bf16
    __shared__ float sb1[FDIM], sb2[FDIM];
    __shared__ float sWl[FDIM * 10];
    __shared__ float sbl[16];

    int tid = threadIdx.x;
    int base = blockIdx.x * 64;

    // stage weights fp32 -> bf16, transposed: thread reads W[k][n0..n0+3] (coalesced float4)
#pragma unroll
    for (int p = 0; p < 4; p++) {
        int idx = tid + p * 256;       // 0..1023
        int k = idx >> 4;
        int n0 = (idx & 15) * 4;
        float4 v1 = ((const float4*)W1)[idx];
        float4 v2 = ((const float4*)W2)[idx];
        sW1t[(n0 + 0) * HP + k] = f2bf(v1.x);
        sW1t[(n0 + 1) * HP + k] = f2bf(v1.y);
        sW1t[(n0 + 2) * HP + k] = f2bf(v1.z);
        sW1t[(n0 + 3) * HP + k] = f2bf(v1.w);
        sW2t[(n0 + 0) * HP + k] = f2bf(v2.x);
        sW2t[(n0 + 1) * HP + k] = f2bf(v2.y);
        sW2t[(n0 + 2) * HP + k] = f2bf(v2.z);
        sW2t[(n0 + 3) * HP + k] = f2bf(v2.w);
    }
    if (tid < FDIM) { sb1[tid] = b1[tid]; sb2[tid] = b2[tid]; }
    if (do_final) {
        for (int i = tid; i < FDIM * 10; i += 256) sWl[i] = Wl[i];
        if (tid < 10) sbl[tid] = bl[tid];
    }
    // stage H tile (bf16, coalesced uint4)
#pragma unroll
    for (int p = 0; p < 2; p++) {
        int idx = tid + p * 256;
        int r = idx >> 3, q = idx & 7;
        uint4 v = make_uint4(0u, 0u, 0u, 0u);
        if (base + r < n_nodes) v = *(const uint4*)(xb + (size_t)(base + r) * FDIM + q * 8);
        *(uint4*)(&sH[r * HP + q * 8]) = v;
    }
    __syncthreads();

    int w = tid >> 6;       // wave id 0..3
    int lane = tid & 63;
    int qd = lane >> 4;     // quad 0..3
    int m = lane & 15;
    int arow = (w * 16 + m) * HP;

    f32x4 acc[4];

    // ---- layer 1: G = relu(H @ W1 + b1) ----
    {
        bf16x8 a0 = *(bf16x8*)(&sH[arow + qd * 8]);
        bf16x8 a1 = *(bf16x8*)(&sH[arow + 32 + qd * 8]);
#pragma unroll
        for (int t = 0; t < 4; t++) {
            float bias = sb1[t * 16 + m];
            acc[t] = (f32x4){bias, bias, bias, bias};
            bf16x8 bA = *(bf16x8*)(&sW1t[(t * 16 + m) * HP + qd * 8]);
            bf16x8 bB = *(bf16x8*)(&sW1t[(t * 16 + m) * HP + 32 + qd * 8]);
            acc[t] = __builtin_amdgcn_mfma_f32_16x16x32_bf16(a0, bA, acc[t], 0, 0, 0);
            acc[t] = __builtin_amdgcn_mfma_f32_16x16x32_bf16(a1, bB, acc[t], 0, 0, 0);
        }
        // write G in place (own rows only; in-wave LDS ordering suffices)
#pragma unroll
        for (int t = 0; t < 4; t++)
#pragma unroll
            for (int r = 0; r < 4; r++)
                sH[(w * 16 + qd * 4 + r) * HP + t * 16 + m] = f2bf(fmaxf(acc[t][r], 0.f));
    }

    // ---- layer 2: O = relu(G @ W2 + b2) ----
    {
        bf16x8 a0 = *(bf16x8*)(&sH[arow + qd * 8]);
        bf16x8 a1 = *(bf16x8*)(&sH[arow + 32 + qd * 8]);
#pragma unroll
        for (int t = 0; t < 4; t++) {
            float bias = sb2[t * 16 + m];
            acc[t] = (f32x4){bias, bias, bias, bias};
            bf16x8 bA = *(bf16x8*)(&sW2t[(t * 16 + m) * HP + qd * 8]);
            bf16x8 bB = *(bf16x8*)(&sW2t[(t * 16 + m) * HP + 32 + qd * 8]);
            acc[t] = __builtin_amdgcn_mfma_f32_16x16x32_bf16(a0, bA, acc[t], 0, 0, 0);
            acc[t] = __builtin_amdgcn_mfma_f32_16x16x32_bf16(a1, bB, acc[t], 0, 0, 0);
        }
#pragma unroll
        for (int t = 0; t < 4; t++)
#pragma unroll
            for (int r = 0; r < 4; r++)
                sH[(w * 16 + qd * 4 + r) * HP + t * 16 + m] = f2bf(fmaxf(acc[t][r], 0.f));
    }
    __syncthreads();

    if (!do_final) {
        // coalesced bf16 store of O
#pragma unroll
        for (int p = 0; p < 2; p++) {
            int idx = tid + p * 256;
            int r = idx >> 3, q = idx & 7;
            if (base + r < n_nodes)
                *(uint4*)(y + (size_t)(base + r) * FDIM + q * 8) = *(uint4*)(&sH[r * HP + q * 8]);
        }
    } else {
        // fused final linear: out[node][c] = O[node][:] . Wl[:,c] + bl[c]
        for (int i = tid; i < 64 * 10; i += 256) {
            int nl = i / 10, cc = i % 10;
            int node = base + nl;
            if (node < n_nodes) {
                float s = sbl[cc];
#pragma unroll
                for (int k0 = 0; k0 < FDIM; k0 += 4) {
                    uint2 hp = *(uint2*)(&sH[nl * HP + k0]);
                    s += bflo(hp.x) * sWl[(k0 + 0) * 10 + cc] + bfhi(hp.x) * sWl[(k0 + 1) * 10 + cc]
                       + bflo(hp.y) * sWl[(k0 + 2) * 10 + cc] + bfhi(hp.y) * sWl[(k0 + 3) * 10 + cc];
                }
                out[(size_t)node * 10 + cc] = s;
            }
        }
    }
}

extern "C" void kernel_launch(void* const* d_in, const int* in_sizes, int n_in,
                              void* d_out, int out_size, void* d_ws, size_t ws_size,
                              hipStream_t stream) {
    const float* features = (const float*)d_in[0];
    const int* edges = (const int*)d_in[1];
    int n_nodes = in_sizes[0] / FDIM;          // 50000
    int n_edges = in_sizes[1] / 2;             // 800000
    const int* src = edges;
    const int* dst = edges + n_edges;

    int nbuck = (n_nodes + BNODES - 1) / BNODES;     // 782
    int nchunks = (n_edges + CHUNK - 1) / CHUNK;     // 98

    // workspace: hist | chunk_off | bucket_total | bucket_start | row_ptr | packed | src_sorted | bf16 bufs
    int* hist = (int*)d_ws;
    int* chunk_off = hist + (size_t)nchunks * nbuck;
    int* bucket_total = chunk_off + (size_t)nchunks * nbuck;
    int* bucket_start = bucket_total + nbuck;
    int* row_ptr = bucket_start + nbuck + 1;
    unsigned int* packed = (unsigned int*)(row_ptr + n_nodes + 1);
    int* src_sorted = (int*)(packed + n_edges);
    size_t int_elems = 2 * (size_t)nchunks * nbuck + 2 * (size_t)nbuck + 2
                       + (size_t)n_nodes + 2 * (size_t)n_edges;
    int_elems = (int_elems + 3) & ~(size_t)3;
    size_t buf_elems = (size_t)n_nodes * FDIM;
    unsigned short* hb  = (unsigned short*)((int*)d_ws + int_elems);
    unsigned short* xb0 = hb + buf_elems;
    unsigned short* yA  = xb0 + buf_elems;
    unsigned short* yB  = yA + buf_elems;

    dim3 bs(256);
    dim3 gs_cast(((int)(buf_elems / 4) + 255) / 256);
    dim3 gs_gather((n_nodes + 15) / 16);   // 3125
    dim3 gs_tile((n_nodes + 63) / 64);     // 782

    // --- cast features to bf16 ---
    cast_bf16<<<gs_cast, bs, 0, stream>>>(features, xb0, (int)(buf_elems / 4));

    // --- build node-grouped CSR via 2-pass bucket sort (deterministic fill) ---
    bucket_hist<<<nchunks, 256, 0, stream>>>(dst, hist, n_edges, nbuck);
    scan_chunks<<<nbuck, 256, 0, stream>>>(hist, chunk_off, bucket_total, nchunks, nbuck);
    scan_buckets<<<1, 1024, 0, stream>>>(bucket_total, bucket_start, row_ptr, nbuck, n_nodes, n_edges);
    bucket_fill<<<nchunks, 256, 0, stream>>>(src, dst, bucket_start, chunk_off, packed, n_edges, nbuck);
    sort_bucket<<<nbuck, 256, 0, stream>>>(packed, bucket_start, src_sorted, row_ptr, n_nodes);

    // --- 3 GIN convs, split gather/MFMA-MLP (last MLP fuses the final linear) ---
    const float* Wl = (const float*)d_in[14];
    const float* bl = (const float*)d_in[15];
    const unsigned short* x_cur = xb0;
    unsigned short* outs[3] = {yA, yB, yA};
    for (int conv = 0; conv < 3; conv++) {
        const float* W1 = (const float*)d_in[2 + 4 * conv];
        const float* b1 = (const float*)d_in[3 + 4 * conv];
        const float* W2 = (const float*)d_in[4 + 4 * conv];
        const float* b2 = (const float*)d_in[5 + 4 * conv];
        int fin = (conv == 2) ? 1 : 0;

        gather_bf16<<<gs_gather, bs, 0, stream>>>(x_cur, row_ptr, src_sorted, hb, n_nodes);
        mlp_mfma<<<gs_tile, bs, 0, stream>>>(hb, W1, b1, W2, b2, Wl, bl,
                                             outs[conv], (float*)d_out, n_nodes, fin);
        x_cur = outs[conv];
    }
}

// Round 13
// 217.017 us; speedup vs baseline: 1.4195x; 1.0310x over previous
//
#include <hip/hip_runtime.h>
#include <hip/hip_bf16.h>

#define FDIM 64
#define BNODES 64          // nodes per bucket (dst >> 6)
#define CHUNK 8192         // edges per partition chunk (98 chunks)
#define HP 72              // padded LDS row stride in shorts
#define GCAP 2048          // staged edge-index capacity per gather block (32 nodes)

typedef short bf16x8 __attribute__((ext_vector_type(8)));
typedef float f32x4 __attribute__((ext_vector_type(4)));

__device__ __forceinline__ unsigned short f2bf(float f) {
    unsigned int u = __float_as_uint(f);
    unsigned int r = (u + 0x7fffu + ((u >> 16) & 1u)) >> 16;   // RNE
    return (unsigned short)r;
}
__device__ __forceinline__ float bflo(unsigned int p) { return __uint_as_float(p << 16); }
__device__ __forceinline__ float bfhi(unsigned int p) { return __uint_as_float(p & 0xffff0000u); }

// ---- cast fp32 -> bf16 (features), 4 elems/thread ----
__global__ __launch_bounds__(256) void cast_bf16(const float* __restrict__ x,
                                                 unsigned short* __restrict__ xb, int n4) {
    int i = blockIdx.x * blockDim.x + threadIdx.x;
    if (i < n4) {
        float4 v = ((const float4*)x)[i];
        uint2 o;
        o.x = (unsigned int)f2bf(v.x) | ((unsigned int)f2bf(v.y) << 16);
        o.y = (unsigned int)f2bf(v.z) | ((unsigned int)f2bf(v.w) << 16);
        ((uint2*)xb)[i] = o;
    }
}

// ---- one-time: cast + transpose the six 64x64 weight matrices to bf16 [n][k] ----
__global__ __launch_bounds__(256) void prep_weights(const float* __restrict__ W10,
                                                    const float* __restrict__ W20,
                                                    const float* __restrict__ W11,
                                                    const float* __restrict__ W21,
                                                    const float* __restrict__ W12,
                                                    const float* __restrict__ W22,
                                                    unsigned short* __restrict__ wt) {
    __shared__ unsigned short s[64 * 64];
    const float* W;
    switch (blockIdx.x) {
        case 0: W = W10; break;
        case 1: W = W20; break;
        case 2: W = W11; break;
        case 3: W = W21; break;
        case 4: W = W12; break;
        default: W = W22; break;
    }
    int tid = threadIdx.x;
#pragma unroll
    for (int p = 0; p < 4; p++) {
        int idx = tid + p * 256;          // 0..1023
        int k = idx >> 4;
        int n0 = (idx & 15) * 4;
        float4 v = ((const float4*)W)[idx];
        s[(n0 + 0) * 64 + k] = f2bf(v.x);
        s[(n0 + 1) * 64 + k] = f2bf(v.y);
        s[(n0 + 2) * 64 + k] = f2bf(v.z);
        s[(n0 + 3) * 64 + k] = f2bf(v.w);
    }
    __syncthreads();
    uint4* o = (uint4*)(wt + (size_t)blockIdx.x * 4096);
#pragma unroll
    for (int p = 0; p < 2; p++) {
        int idx = tid + p * 256;          // 0..511
        o[idx] = ((uint4*)s)[idx];
    }
}

// ---- pass 1: per-chunk bucket histogram (LDS) ----
__global__ __launch_bounds__(256) void bucket_hist(const int* __restrict__ dst,
                                                   int* __restrict__ hist,
                                                   int n_edges, int nbuck) {
    __shared__ int lh[1024];
    int chunk = blockIdx.x;
    for (int i = threadIdx.x; i < nbuck; i += 256) lh[i] = 0;
    __syncthreads();
    int beg = chunk * CHUNK;
    int end = min(beg + CHUNK, n_edges);
    for (int e = beg + threadIdx.x; e < end; e += 256)
        atomicAdd(&lh[dst[e] >> 6], 1);
    __syncthreads();
    for (int i = threadIdx.x; i < nbuck; i += 256)
        hist[(size_t)chunk * nbuck + i] = lh[i];
}

// ---- pass 2a: per-bucket exclusive scan over chunks (nchunks <= 256) ----
__global__ __launch_bounds__(256) void scan_chunks(const int* __restrict__ hist,
                                                   int* __restrict__ chunk_off,
                                                   int* __restrict__ bucket_total,
                                                   int nchunks, int nbuck) {
    __shared__ int s[256];
    int b = blockIdx.x;
    int t = threadIdx.x;
    int v = (t < nchunks) ? hist[(size_t)t * nbuck + b] : 0;
    s[t] = v;
    __syncthreads();
    for (int off = 1; off < 256; off <<= 1) {
        int u = (t >= off) ? s[t - off] : 0;
        __syncthreads();
        s[t] += u;
        __syncthreads();
    }
    if (t < nchunks) chunk_off[(size_t)t * nbuck + b] = s[t] - v;  // exclusive
    if (t == 255) bucket_total[b] = s[255];
}

// ---- pass 2b: exclusive scan of bucket totals ----
__global__ __launch_bounds__(1024) void scan_buckets(const int* __restrict__ bucket_total,
                                                     int* __restrict__ bucket_start,
                                                     int* __restrict__ row_ptr,
                                                     int nbuck, int n_nodes, int n_edges) {
    __shared__ int s[1024];
    int t = threadIdx.x;
    int v = (t < nbuck) ? bucket_total[t] : 0;
    s[t] = v;
    __syncthreads();
    for (int off = 1; off < 1024; off <<= 1) {
        int u = (t >= off) ? s[t - off] : 0;
        __syncthreads();
        s[t] += u;
        __syncthreads();
    }
    if (t < nbuck) bucket_start[t] = s[t] - v;
    if (t == 0) { bucket_start[nbuck] = n_edges; row_ptr[n_nodes] = n_edges; }
}

// ---- pass 3: fill packed edges, (chunk,bucket)-contiguous runs ----
__global__ __launch_bounds__(256) void bucket_fill(const int* __restrict__ src,
                                                   const int* __restrict__ dst,
                                                   const int* __restrict__ bucket_start,
                                                   const int* __restrict__ chunk_off,
                                                   unsigned int* __restrict__ packed,
                                                   int n_edges, int nbuck) {
    __shared__ int cur[1024];
    int chunk = blockIdx.x;
    for (int i = threadIdx.x; i < nbuck; i += 256)
        cur[i] = bucket_start[i] + chunk_off[(size_t)chunk * nbuck + i];
    __syncthreads();
    int beg = chunk * CHUNK;
    int end = min(beg + CHUNK, n_edges);
    for (int e = beg + threadIdx.x; e < end; e += 256) {
        int d = dst[e];
        int b = d >> 6;
        int pos = atomicAdd(&cur[b], 1);
        packed[pos] = (unsigned int)src[e] | ((unsigned int)(d & 63) << 16);
    }
}

// ---- pass 4: within-bucket sort to node granularity + row_ptr emit ----
__global__ __launch_bounds__(256) void sort_bucket(const unsigned int* __restrict__ packed,
                                                   const int* __restrict__ bucket_start,
                                                   int* __restrict__ src_sorted,
                                                   int* __restrict__ row_ptr, int n_nodes) {
    __shared__ int cnt[BNODES];
    __shared__ int cur[BNODES];
    int b = blockIdx.x;
    int beg = bucket_start[b], end = bucket_start[b + 1];
    if (threadIdx.x < BNODES) cnt[threadIdx.x] = 0;
    __syncthreads();
    for (int e = beg + threadIdx.x; e < end; e += 256)
        atomicAdd(&cnt[packed[e] >> 16], 1);
    __syncthreads();
    if (threadIdx.x < 64) {
        int v = cnt[threadIdx.x];
        int inc = v;
#pragma unroll
        for (int off = 1; off < 64; off <<= 1) {
            int u = __shfl_up(inc, off, 64);
            if (threadIdx.x >= off) inc += u;
        }
        cur[threadIdx.x] = beg + inc - v;     // exclusive
        int node = b * BNODES + threadIdx.x;
        if (node < n_nodes) row_ptr[node] = beg + inc - v;
    }
    __syncthreads();
    for (int e = beg + threadIdx.x; e < end; e += 256) {
        unsigned int p = packed[e];
        int pos = atomicAdd(&cur[p >> 16], 1);
        src_sorted[pos] = (int)(p & 0xFFFFu);
    }
}

// gather (bf16 in/out, fp32 accum): 32 nodes/block, 8 threads/node, 16B/lane loads.
__global__ __launch_bounds__(256) void gather_bf16(const unsigned short* __restrict__ xb,
                                                   const int* __restrict__ row_ptr,
                                                   const int* __restrict__ src_sorted,
                                                   unsigned short* __restrict__ hb,
                                                   int n_nodes) {
    __shared__ int sidx[GCAP];
    int base = blockIdx.x * 32;
    int ebeg = row_ptr[base];
    int eend = row_ptr[min(base + 32, n_nodes)];
    int total = eend - ebeg;
    int cnt = min(total, GCAP);
    for (int i = threadIdx.x; i < cnt; i += 256) sidx[i] = src_sorted[ebeg + i];
    __syncthreads();

    int t = threadIdx.x;
    int node = base + (t >> 3);
    if (node >= n_nodes) return;
    int c = (t & 7) * 8;                  // 8 bf16 = 16B per lane
    int dbeg = row_ptr[node] - ebeg;
    int dend = row_ptr[node + 1] - ebeg;
    int dmid = (total <= GCAP) ? dend : min(dend, cnt);

    float acc[8];
    {
        uint4 v = *(const uint4*)(xb + (size_t)node * FDIM + c);
        acc[0] = bflo(v.x); acc[1] = bfhi(v.x);
        acc[2] = bflo(v.y); acc[3] = bfhi(v.y);
        acc[4] = bflo(v.z); acc[5] = bfhi(v.z);
        acc[6] = bflo(v.w); acc[7] = bfhi(v.w);
    }

    int e = dbeg;
    for (; e + 7 < dmid; e += 8) {
        int s[8];
#pragma unroll
        for (int j = 0; j < 8; j++) s[j] = sidx[e + j];
        uint4 v[8];
#pragma unroll
        for (int j = 0; j < 8; j++) v[j] = *(const uint4*)(xb + (size_t)s[j] * FDIM + c);
#pragma unroll
        for (int j = 0; j < 8; j++) {
            acc[0] += bflo(v[j].x); acc[1] += bfhi(v[j].x);
            acc[2] += bflo(v[j].y); acc[3] += bfhi(v[j].y);
            acc[4] += bflo(v[j].z); acc[5] += bfhi(v[j].z);
            acc[6] += bflo(v[j].w); acc[7] += bfhi(v[j].w);
        }
    }
    if (e + 3 < dmid) {
        int s[4];
#pragma unroll
        for (int j = 0; j < 4; j++) s[j] = sidx[e + j];
        uint4 v[4];
#pragma unroll
        for (int j = 0; j < 4; j++) v[j] = *(const uint4*)(xb + (size_t)s[j] * FDIM + c);
#pragma unroll
        for (int j = 0; j < 4; j++) {
            acc[0] += bflo(v[j].x); acc[1] += bfhi(v[j].x);
            acc[2] += bflo(v[j].y); acc[3] += bfhi(v[j].y);
            acc[4] += bflo(v[j].z); acc[5] += bfhi(v[j].z);
            acc[6] += bflo(v[j].w); acc[7] += bfhi(v[j].w);
        }
        e += 4;
    }
    for (; e < dmid; e++) {
        uint4 v = *(const uint4*)(xb + (size_t)sidx[e] * FDIM + c);
        acc[0] += bflo(v.x); acc[1] += bfhi(v.x);
        acc[2] += bflo(v.y); acc[3] += bfhi(v.y);
        acc[4] += bflo(v.z); acc[5] += bfhi(v.z);
        acc[6] += bflo(v.w); acc[7] += bfhi(v.w);
    }
    for (; e < dend; e++) {               // overflow tail (virtually never)
        uint4 v = *(const uint4*)(xb + (size_t)src_sorted[ebeg + e] * FDIM + c);
        acc[0] += bflo(v.x); acc[1] += bfhi(v.x);
        acc[2] += bflo(v.y); acc[3] += bfhi(v.y);
        acc[4] += bflo(v.z); acc[5] += bfhi(v.z);
        acc[6] += bflo(v.w); acc[7] += bfhi(v.w);
    }

    uint4 p;
    p.x = (unsigned int)f2bf(acc[0]) | ((unsigned int)f2bf(acc[1]) << 16);
    p.y = (unsigned int)f2bf(acc[2]) | ((unsigned int)f2bf(acc[3]) << 16);
    p.z = (unsigned int)f2bf(acc[4]) | ((unsigned int)f2bf(acc[5]) << 16);
    p.w = (unsigned int)f2bf(acc[6]) | ((unsigned int)f2bf(acc[7]) << 16);
    *(uint4*)(hb + (size_t)node * FDIM + c) = p;
}

// ---- MFMA MLP over a 64-node tile; weights pre-transposed bf16 [n][k] in global ----
__global__ __launch_bounds__(256) void mlp_mfma(const unsigned short* __restrict__ xb,
        const unsigned short* __restrict__ wt1, const float* __restrict__ b1,
        const unsigned short* __restrict__ wt2, const float* __restrict__ b2,
        const float* __restrict__ Wl, const float* __restrict__ bl,
        unsigned short* __restrict__ y, float* __restrict__ out,
        int n_nodes, int do_final) {
    __shared__ unsigned short sH[64 * HP];      // H -> G -> O (bf16)
    __shared__ unsigned short sW1t[64 * HP];    // W1^T [n][k] bf16
    __shared__ unsigned short sW2t[64 * HP];    // W2^T [n][k] bf16
    __shared__ float sb1[FDIM], sb2[FDIM];
    __shared__ float sWl[FDIM * 10];
    __shared__ float sbl[16];

    int tid = threadIdx.x;
    int base = blockIdx.x * 64;

    // stage pre-transposed weights: 512 uint4 each, 2 per thread per matrix
    {
        const uint4* w1g = (const uint4*)wt1;
        const uint4* w2g = (const uint4*)wt2;
#pragma unroll
        for (int p = 0; p < 2; p++) {
            int idx = tid + p * 256;       // 0..511
            int r = idx >> 3, q = idx & 7;
            *(uint4*)(&sW1t[r * HP + q * 8]) = w1g[idx];
            *(uint4*)(&sW2t[r * HP + q * 8]) = w2g[idx];
        }
    }
    if (tid < FDIM) { sb1[tid] = b1[tid]; sb2[tid] = b2[tid]; }
    if (do_final) {
        for (int i = tid; i < FDIM * 10; i += 256) sWl[i] = Wl[i];
        if (tid < 10) sbl[tid] = bl[tid];
    }
    // stage H tile (bf16, coalesced uint4)
#pragma unroll
    for (int p = 0; p < 2; p++) {
        int idx = tid + p * 256;
        int r = idx >> 3, q = idx & 7;
        uint4 v = make_uint4(0u, 0u, 0u, 0u);
        if (base + r < n_nodes) v = *(const uint4*)(xb + (size_t)(base + r) * FDIM + q * 8);
        *(uint4*)(&sH[r * HP + q * 8]) = v;
    }
    __syncthreads();

    int w = tid >> 6;       // wave id 0..3
    int lane = tid & 63;
    int qd = lane >> 4;     // quad 0..3
    int m = lane & 15;
    int arow = (w * 16 + m) * HP;

    f32x4 acc[4];

    // ---- layer 1: G = relu(H @ W1 + b1) ----
    {
        bf16x8 a0 = *(bf16x8*)(&sH[arow + qd * 8]);
        bf16x8 a1 = *(bf16x8*)(&sH[arow + 32 + qd * 8]);
#pragma unroll
        for (int t = 0; t < 4; t++) {
            float bias = sb1[t * 16 + m];
            acc[t] = (f32x4){bias, bias, bias, bias};
            bf16x8 bA = *(bf16x8*)(&sW1t[(t * 16 + m) * HP + qd * 8]);
            bf16x8 bB = *(bf16x8*)(&sW1t[(t * 16 + m) * HP + 32 + qd * 8]);
            acc[t] = __builtin_amdgcn_mfma_f32_16x16x32_bf16(a0, bA, acc[t], 0, 0, 0);
            acc[t] = __builtin_amdgcn_mfma_f32_16x16x32_bf16(a1, bB, acc[t], 0, 0, 0);
        }
#pragma unroll
        for (int t = 0; t < 4; t++)
#pragma unroll
            for (int r = 0; r < 4; r++)
                sH[(w * 16 + qd * 4 + r) * HP + t * 16 + m] = f2bf(fmaxf(acc[t][r], 0.f));
    }

    // ---- layer 2: O = relu(G @ W2 + b2) ----
    {
        bf16x8 a0 = *(bf16x8*)(&sH[arow + qd * 8]);
        bf16x8 a1 = *(bf16x8*)(&sH[arow + 32 + qd * 8]);
#pragma unroll
        for (int t = 0; t < 4; t++) {
            float bias = sb2[t * 16 + m];
            acc[t] = (f32x4){bias, bias, bias, bias};
            bf16x8 bA = *(bf16x8*)(&sW2t[(t * 16 + m) * HP + qd * 8]);
            bf16x8 bB = *(bf16x8*)(&sW2t[(t * 16 + m) * HP + 32 + qd * 8]);
            acc[t] = __builtin_amdgcn_mfma_f32_16x16x32_bf16(a0, bA, acc[t], 0, 0, 0);
            acc[t] = __builtin_amdgcn_mfma_f32_16x16x32_bf16(a1, bB, acc[t], 0, 0, 0);
        }
#pragma unroll
        for (int t = 0; t < 4; t++)
#pragma unroll
            for (int r = 0; r < 4; r++)
                sH[(w * 16 + qd * 4 + r) * HP + t * 16 + m] = f2bf(fmaxf(acc[t][r], 0.f));
    }
    __syncthreads();

    if (!do_final) {
#pragma unroll
        for (int p = 0; p < 2; p++) {
            int idx = tid + p * 256;
            int r = idx >> 3, q = idx & 7;
            if (base + r < n_nodes)
                *(uint4*)(y + (size_t)(base + r) * FDIM + q * 8) = *(uint4*)(&sH[r * HP + q * 8]);
        }
    } else {
        for (int i = tid; i < 64 * 10; i += 256) {
            int nl = i / 10, cc = i % 10;
            int node = base + nl;
            if (node < n_nodes) {
                float s = sbl[cc];
#pragma unroll
                for (int k0 = 0; k0 < FDIM; k0 += 4) {
                    uint2 hp = *(uint2*)(&sH[nl * HP + k0]);
                    s += bflo(hp.x) * sWl[(k0 + 0) * 10 + cc] + bfhi(hp.x) * sWl[(k0 + 1) * 10 + cc]
                       + bflo(hp.y) * sWl[(k0 + 2) * 10 + cc] + bfhi(hp.y) * sWl[(k0 + 3) * 10 + cc];
                }
                out[(size_t)node * 10 + cc] = s;
            }
        }
    }
}

extern "C" void kernel_launch(void* const* d_in, const int* in_sizes, int n_in,
                              void* d_out, int out_size, void* d_ws, size_t ws_size,
                              hipStream_t stream) {
    const float* features = (const float*)d_in[0];
    const int* edges = (const int*)d_in[1];
    int n_nodes = in_sizes[0] / FDIM;          // 50000
    int n_edges = in_sizes[1] / 2;             // 800000
    const int* src = edges;
    const int* dst = edges + n_edges;

    int nbuck = (n_nodes + BNODES - 1) / BNODES;     // 782
    int nchunks = (n_edges + CHUNK - 1) / CHUNK;     // 98

    // workspace: hist | chunk_off | bucket_total | bucket_start | row_ptr | packed | src_sorted | bf16 bufs | wt
    int* hist = (int*)d_ws;
    int* chunk_off = hist + (size_t)nchunks * nbuck;
    int* bucket_total = chunk_off + (size_t)nchunks * nbuck;
    int* bucket_start = bucket_total + nbuck;
    int* row_ptr = bucket_start + nbuck + 1;
    unsigned int* packed = (unsigned int*)(row_ptr + n_nodes + 1);
    int* src_sorted = (int*)(packed + n_edges);
    size_t int_elems = 2 * (size_t)nchunks * nbuck + 2 * (size_t)nbuck + 2
                       + (size_t)n_nodes + 2 * (size_t)n_edges;
    int_elems = (int_elems + 3) & ~(size_t)3;
    size_t buf_elems = (size_t)n_nodes * FDIM;
    unsigned short* hb  = (unsigned short*)((int*)d_ws + int_elems);
    unsigned short* xb0 = hb + buf_elems;
    unsigned short* yA  = xb0 + buf_elems;
    unsigned short* yB  = yA + buf_elems;
    unsigned short* wt  = yB + buf_elems;     // 6 * 4096 bf16 (48 KB)

    dim3 bs(256);
    dim3 gs_cast(((int)(buf_elems / 4) + 255) / 256);
    dim3 gs_gather((n_nodes + 31) / 32);   // 1563
    dim3 gs_tile((n_nodes + 63) / 64);     // 782

    // --- cast features; pre-transpose weights ---
    cast_bf16<<<gs_cast, bs, 0, stream>>>(features, xb0, (int)(buf_elems / 4));
    prep_weights<<<6, bs, 0, stream>>>((const float*)d_in[2], (const float*)d_in[4],
                                       (const float*)d_in[6], (const float*)d_in[8],
                                       (const float*)d_in[10], (const float*)d_in[12], wt);

    // --- build node-grouped CSR via 2-pass bucket sort (deterministic fill) ---
    bucket_hist<<<nchunks, 256, 0, stream>>>(dst, hist, n_edges, nbuck);
    scan_chunks<<<nbuck, 256, 0, stream>>>(hist, chunk_off, bucket_total, nchunks, nbuck);
    scan_buckets<<<1, 1024, 0, stream>>>(bucket_total, bucket_start, row_ptr, nbuck, n_nodes, n_edges);
    bucket_fill<<<nchunks, 256, 0, stream>>>(src, dst, bucket_start, chunk_off, packed, n_edges, nbuck);
    sort_bucket<<<nbuck, 256, 0, stream>>>(packed, bucket_start, src_sorted, row_ptr, n_nodes);

    // --- 3 GIN convs, split gather/MFMA-MLP (last MLP fuses the final linear) ---
    const float* Wl = (const float*)d_in[14];
    const float* bl = (const float*)d_in[15];
    const unsigned short* x_cur = xb0;
    unsigned short* outs[3] = {yA, yB, yA};
    for (int conv = 0; conv < 3; conv++) {
        const float* b1 = (const float*)d_in[3 + 4 * conv];
        const float* b2 = (const float*)d_in[5 + 4 * conv];
        const unsigned short* wt1 = wt + (size_t)(2 * conv) * 4096;
        const unsigned short* wt2 = wt + (size_t)(2 * conv + 1) * 4096;
        int fin = (conv == 2) ? 1 : 0;

        gather_bf16<<<gs_gather, bs, 0, stream>>>(x_cur, row_ptr, src_sorted, hb, n_nodes);
        mlp_mfma<<<gs_tile, bs, 0, stream>>>(hb, wt1, b1, wt2, b2, Wl, bl,
                                             outs[conv], (float*)d_out, n_nodes, fin);
        x_cur = outs[conv];
    }
}

// Round 14
// 196.562 us; speedup vs baseline: 1.5672x; 1.1041x over previous
//
#include <hip/hip_runtime.h>
#include <hip/hip_bf16.h>

#define FDIM 64
#define BNODES 64          // nodes per bucket (dst >> 6)
#define CHUNK 4096         // edges per partition chunk (196 chunks -> 77% CU coverage)
#define HP 72              // padded LDS row stride in shorts
#define GCAP 2048          // staged edge-index capacity per gather block (32 nodes)

typedef short bf16x8 __attribute__((ext_vector_type(8)));
typedef float f32x4 __attribute__((ext_vector_type(4)));

__device__ __forceinline__ unsigned short f2bf(float f) {
    unsigned int u = __float_as_uint(f);
    unsigned int r = (u + 0x7fffu + ((u >> 16) & 1u)) >> 16;   // RNE
    return (unsigned short)r;
}
__device__ __forceinline__ float bflo(unsigned int p) { return __uint_as_float(p << 16); }
__device__ __forceinline__ float bfhi(unsigned int p) { return __uint_as_float(p & 0xffff0000u); }

// ---- fused: cast features fp32->bf16 (blocks 0..ncast-1) + transpose 6 weight
// matrices to bf16 [n][k] (blocks ncast..ncast+5) ----
__global__ __launch_bounds__(256) void cast_and_prep(const float* __restrict__ x,
                                                     unsigned short* __restrict__ xb, int n4,
                                                     int ncast,
                                                     const float* __restrict__ W10,
                                                     const float* __restrict__ W20,
                                                     const float* __restrict__ W11,
                                                     const float* __restrict__ W21,
                                                     const float* __restrict__ W12,
                                                     const float* __restrict__ W22,
                                                     unsigned short* __restrict__ wt) {
    __shared__ unsigned short s[64 * 64];
    int tid = threadIdx.x;
    if (blockIdx.x < (unsigned)ncast) {
        int i = blockIdx.x * 256 + tid;
        if (i < n4) {
            float4 v = ((const float4*)x)[i];
            uint2 o;
            o.x = (unsigned int)f2bf(v.x) | ((unsigned int)f2bf(v.y) << 16);
            o.y = (unsigned int)f2bf(v.z) | ((unsigned int)f2bf(v.w) << 16);
            ((uint2*)xb)[i] = o;
        }
        return;
    }
    int wsel = blockIdx.x - ncast;     // 0..5
    const float* W;
    switch (wsel) {
        case 0: W = W10; break;
        case 1: W = W20; break;
        case 2: W = W11; break;
        case 3: W = W21; break;
        case 4: W = W12; break;
        default: W = W22; break;
    }
#pragma unroll
    for (int p = 0; p < 4; p++) {
        int idx = tid + p * 256;          // 0..1023
        int k = idx >> 4;
        int n0 = (idx & 15) * 4;
        float4 v = ((const float4*)W)[idx];
        s[(n0 + 0) * 64 + k] = f2bf(v.x);
        s[(n0 + 1) * 64 + k] = f2bf(v.y);
        s[(n0 + 2) * 64 + k] = f2bf(v.z);
        s[(n0 + 3) * 64 + k] = f2bf(v.w);
    }
    __syncthreads();
    uint4* o = (uint4*)(wt + (size_t)wsel * 4096);
#pragma unroll
    for (int p = 0; p < 2; p++) {
        int idx = tid + p * 256;          // 0..511
        o[idx] = ((uint4*)s)[idx];
    }
}

// ---- pass 1: per-chunk bucket histogram (LDS) ----
__global__ __launch_bounds__(256) void bucket_hist(const int* __restrict__ dst,
                                                   int* __restrict__ hist,
                                                   int n_edges, int nbuck) {
    __shared__ int lh[1024];
    int chunk = blockIdx.x;
    for (int i = threadIdx.x; i < nbuck; i += 256) lh[i] = 0;
    __syncthreads();
    int beg = chunk * CHUNK;
    int end = min(beg + CHUNK, n_edges);
    for (int e = beg + threadIdx.x; e < end; e += 256)
        atomicAdd(&lh[dst[e] >> 6], 1);
    __syncthreads();
    for (int i = threadIdx.x; i < nbuck; i += 256)
        hist[(size_t)chunk * nbuck + i] = lh[i];
}

// ---- pass 2a: per-bucket exclusive scan over chunks (nchunks <= 256) ----
__global__ __launch_bounds__(256) void scan_chunks(const int* __restrict__ hist,
                                                   int* __restrict__ chunk_off,
                                                   int* __restrict__ bucket_total,
                                                   int nchunks, int nbuck) {
    __shared__ int s[256];
    int b = blockIdx.x;
    int t = threadIdx.x;
    int v = (t < nchunks) ? hist[(size_t)t * nbuck + b] : 0;
    s[t] = v;
    __syncthreads();
    for (int off = 1; off < 256; off <<= 1) {
        int u = (t >= off) ? s[t - off] : 0;
        __syncthreads();
        s[t] += u;
        __syncthreads();
    }
    if (t < nchunks) chunk_off[(size_t)t * nbuck + b] = s[t] - v;  // exclusive
    if (t == 255) bucket_total[b] = s[255];
}

// ---- pass 2b: exclusive scan of bucket totals ----
__global__ __launch_bounds__(1024) void scan_buckets(const int* __restrict__ bucket_total,
                                                     int* __restrict__ bucket_start,
                                                     int* __restrict__ row_ptr,
                                                     int nbuck, int n_nodes, int n_edges) {
    __shared__ int s[1024];
    int t = threadIdx.x;
    int v = (t < nbuck) ? bucket_total[t] : 0;
    s[t] = v;
    __syncthreads();
    for (int off = 1; off < 1024; off <<= 1) {
        int u = (t >= off) ? s[t - off] : 0;
        __syncthreads();
        s[t] += u;
        __syncthreads();
    }
    if (t < nbuck) bucket_start[t] = s[t] - v;
    if (t == 0) { bucket_start[nbuck] = n_edges; row_ptr[n_nodes] = n_edges; }
}

// ---- pass 3: fill packed edges, (chunk,bucket)-contiguous runs ----
__global__ __launch_bounds__(256) void bucket_fill(const int* __restrict__ src,
                                                   const int* __restrict__ dst,
                                                   const int* __restrict__ bucket_start,
                                                   const int* __restrict__ chunk_off,
                                                   unsigned int* __restrict__ packed,
                                                   int n_edges, int nbuck) {
    __shared__ int cur[1024];
    int chunk = blockIdx.x;
    for (int i = threadIdx.x; i < nbuck; i += 256)
        cur[i] = bucket_start[i] + chunk_off[(size_t)chunk * nbuck + i];
    __syncthreads();
    int beg = chunk * CHUNK;
    int end = min(beg + CHUNK, n_edges);
    for (int e = beg + threadIdx.x; e < end; e += 256) {
        int d = dst[e];
        int b = d >> 6;
        int pos = atomicAdd(&cur[b], 1);
        packed[pos] = (unsigned int)src[e] | ((unsigned int)(d & 63) << 16);
    }
}

// ---- pass 4: within-bucket sort to node granularity + row_ptr emit ----
__global__ __launch_bounds__(256) void sort_bucket(const unsigned int* __restrict__ packed,
                                                   const int* __restrict__ bucket_start,
                                                   int* __restrict__ src_sorted,
                                                   int* __restrict__ row_ptr, int n_nodes) {
    __shared__ int cnt[BNODES];
    __shared__ int cur[BNODES];
    int b = blockIdx.x;
    int beg = bucket_start[b], end = bucket_start[b + 1];
    if (threadIdx.x < BNODES) cnt[threadIdx.x] = 0;
    __syncthreads();
    for (int e = beg + threadIdx.x; e < end; e += 256)
        atomicAdd(&cnt[packed[e] >> 16], 1);
    __syncthreads();
    if (threadIdx.x < 64) {
        int v = cnt[threadIdx.x];
        int inc = v;
#pragma unroll
        for (int off = 1; off < 64; off <<= 1) {
            int u = __shfl_up(inc, off, 64);
            if (threadIdx.x >= off) inc += u;
        }
        cur[threadIdx.x] = beg + inc - v;     // exclusive
        int node = b * BNODES + threadIdx.x;
        if (node < n_nodes) row_ptr[node] = beg + inc - v;
    }
    __syncthreads();
    for (int e = beg + threadIdx.x; e < end; e += 256) {
        unsigned int p = packed[e];
        int pos = atomicAdd(&cur[p >> 16], 1);
        src_sorted[pos] = (int)(p & 0xFFFFu);
    }
}

// gather (bf16 in/out, fp32 accum): 32 nodes/block, 8 threads/node, 16B/lane loads.
__global__ __launch_bounds__(256) void gather_bf16(const unsigned short* __restrict__ xb,
                                                   const int* __restrict__ row_ptr,
                                                   const int* __restrict__ src_sorted,
                                                   unsigned short* __restrict__ hb,
                                                   int n_nodes) {
    __shared__ int sidx[GCAP];
    int base = blockIdx.x * 32;
    int ebeg = row_ptr[base];
    int eend = row_ptr[min(base + 32, n_nodes)];
    int total = eend - ebeg;
    int cnt = min(total, GCAP);
    for (int i = threadIdx.x; i < cnt; i += 256) sidx[i] = src_sorted[ebeg + i];
    __syncthreads();

    int t = threadIdx.x;
    int node = base + (t >> 3);
    if (node >= n_nodes) return;
    int c = (t & 7) * 8;                  // 8 bf16 = 16B per lane
    int dbeg = row_ptr[node] - ebeg;
    int dend = row_ptr[node + 1] - ebeg;
    int dmid = (total <= GCAP) ? dend : min(dend, cnt);

    float acc[8];
    {
        uint4 v = *(const uint4*)(xb + (size_t)node * FDIM + c);
        acc[0] = bflo(v.x); acc[1] = bfhi(v.x);
        acc[2] = bflo(v.y); acc[3] = bfhi(v.y);
        acc[4] = bflo(v.z); acc[5] = bfhi(v.z);
        acc[6] = bflo(v.w); acc[7] = bfhi(v.w);
    }

    int e = dbeg;
    for (; e + 7 < dmid; e += 8) {
        int s[8];
#pragma unroll
        for (int j = 0; j < 8; j++) s[j] = sidx[e + j];
        uint4 v[8];
#pragma unroll
        for (int j = 0; j < 8; j++) v[j] = *(const uint4*)(xb + (size_t)s[j] * FDIM + c);
#pragma unroll
        for (int j = 0; j < 8; j++) {
            acc[0] += bflo(v[j].x); acc[1] += bfhi(v[j].x);
            acc[2] += bflo(v[j].y); acc[3] += bfhi(v[j].y);
            acc[4] += bflo(v[j].z); acc[5] += bfhi(v[j].z);
            acc[6] += bflo(v[j].w); acc[7] += bfhi(v[j].w);
        }
    }
    if (e + 3 < dmid) {
        int s[4];
#pragma unroll
        for (int j = 0; j < 4; j++) s[j] = sidx[e + j];
        uint4 v[4];
#pragma unroll
        for (int j = 0; j < 4; j++) v[j] = *(const uint4*)(xb + (size_t)s[j] * FDIM + c);
#pragma unroll
        for (int j = 0; j < 4; j++) {
            acc[0] += bflo(v[j].x); acc[1] += bfhi(v[j].x);
            acc[2] += bflo(v[j].y); acc[3] += bfhi(v[j].y);
            acc[4] += bflo(v[j].z); acc[5] += bfhi(v[j].z);
            acc[6] += bflo(v[j].w); acc[7] += bfhi(v[j].w);
        }
        e += 4;
    }
    for (; e < dmid; e++) {
        uint4 v = *(const uint4*)(xb + (size_t)sidx[e] * FDIM + c);
        acc[0] += bflo(v.x); acc[1] += bfhi(v.x);
        acc[2] += bflo(v.y); acc[3] += bfhi(v.y);
        acc[4] += bflo(v.z); acc[5] += bfhi(v.z);
        acc[6] += bflo(v.w); acc[7] += bfhi(v.w);
    }
    for (; e < dend; e++) {               // overflow tail (virtually never)
        uint4 v = *(const uint4*)(xb + (size_t)src_sorted[ebeg + e] * FDIM + c);
        acc[0] += bflo(v.x); acc[1] += bfhi(v.x);
        acc[2] += bflo(v.y); acc[3] += bfhi(v.y);
        acc[4] += bflo(v.z); acc[5] += bfhi(v.z);
        acc[6] += bflo(v.w); acc[7] += bfhi(v.w);
    }

    uint4 p;
    p.x = (unsigned int)f2bf(acc[0]) | ((unsigned int)f2bf(acc[1]) << 16);
    p.y = (unsigned int)f2bf(acc[2]) | ((unsigned int)f2bf(acc[3]) << 16);
    p.z = (unsigned int)f2bf(acc[4]) | ((unsigned int)f2bf(acc[5]) << 16);
    p.w = (unsigned int)f2bf(acc[6]) | ((unsigned int)f2bf(acc[7]) << 16);
    *(uint4*)(hb + (size_t)node * FDIM + c) = p;
}

// ---- MFMA MLP over a 64-node tile; weights pre-transposed bf16 [n][k] in global ----
__global__ __launch_bounds__(256) void mlp_mfma(const unsigned short* __restrict__ xb,
        const unsigned short* __restrict__ wt1, const float* __restrict__ b1,
        const unsigned short* __restrict__ wt2, const float* __restrict__ b2,
        const float* __restrict__ Wl, const float* __restrict__ bl,
        unsigned short* __restrict__ y, float* __restrict__ out,
        int n_nodes, int do_final) {
    __shared__ unsigned short sH[64 * HP];      // H -> G -> O (bf16)
    __shared__ unsigned short sW1t[64 * HP];    // W1^T [n][k] bf16
    __shared__ unsigned short sW2t[64 * HP];    // W2^T [n][k] bf16
    __shared__ float sb1[FDIM], sb2[FDIM];
    __shared__ float sWl[FDIM * 10];
    __shared__ float sbl[16];

    int tid = threadIdx.x;
    int base = blockIdx.x * 64;

    {
        const uint4* w1g = (const uint4*)wt1;
        const uint4* w2g = (const uint4*)wt2;
#pragma unroll
        for (int p = 0; p < 2; p++) {
            int idx = tid + p * 256;       // 0..511
            int r = idx >> 3, q = idx & 7;
            *(uint4*)(&sW1t[r * HP + q * 8]) = w1g[idx];
            *(uint4*)(&sW2t[r * HP + q * 8]) = w2g[idx];
        }
    }
    if (tid < FDIM) { sb1[tid] = b1[tid]; sb2[tid] = b2[tid]; }
    if (do_final) {
        for (int i = tid; i < FDIM * 10; i += 256) sWl[i] = Wl[i];
        if (tid < 10) sbl[tid] = bl[tid];
    }
#pragma unroll
    for (int p = 0; p < 2; p++) {
        int idx = tid + p * 256;
        int r = idx >> 3, q = idx & 7;
        uint4 v = make_uint4(0u, 0u, 0u, 0u);
        if (base + r < n_nodes) v = *(const uint4*)(xb + (size_t)(base + r) * FDIM + q * 8);
        *(uint4*)(&sH[r * HP + q * 8]) = v;
    }
    __syncthreads();

    int w = tid >> 6;       // wave id 0..3
    int lane = tid & 63;
    int qd = lane >> 4;     // quad 0..3
    int m = lane & 15;
    int arow = (w * 16 + m) * HP;

    f32x4 acc[4];

    // ---- layer 1: G = relu(H @ W1 + b1) ----
    {
        bf16x8 a0 = *(bf16x8*)(&sH[arow + qd * 8]);
        bf16x8 a1 = *(bf16x8*)(&sH[arow + 32 + qd * 8]);
#pragma unroll
        for (int t = 0; t < 4; t++) {
            float bias = sb1[t * 16 + m];
            acc[t] = (f32x4){bias, bias, bias, bias};
            bf16x8 bA = *(bf16x8*)(&sW1t[(t * 16 + m) * HP + qd * 8]);
            bf16x8 bB = *(bf16x8*)(&sW1t[(t * 16 + m) * HP + 32 + qd * 8]);
            acc[t] = __builtin_amdgcn_mfma_f32_16x16x32_bf16(a0, bA, acc[t], 0, 0, 0);
            acc[t] = __builtin_amdgcn_mfma_f32_16x16x32_bf16(a1, bB, acc[t], 0, 0, 0);
        }
#pragma unroll
        for (int t = 0; t < 4; t++)
#pragma unroll
            for (int r = 0; r < 4; r++)
                sH[(w * 16 + qd * 4 + r) * HP + t * 16 + m] = f2bf(fmaxf(acc[t][r], 0.f));
    }

    // ---- layer 2: O = relu(G @ W2 + b2) ----
    {
        bf16x8 a0 = *(bf16x8*)(&sH[arow + qd * 8]);
        bf16x8 a1 = *(bf16x8*)(&sH[arow + 32 + qd * 8]);
#pragma unroll
        for (int t = 0; t < 4; t++) {
            float bias = sb2[t * 16 + m];
            acc[t] = (f32x4){bias, bias, bias, bias};
            bf16x8 bA = *(bf16x8*)(&sW2t[(t * 16 + m) * HP + qd * 8]);
            bf16x8 bB = *(bf16x8*)(&sW2t[(t * 16 + m) * HP + 32 + qd * 8]);
            acc[t] = __builtin_amdgcn_mfma_f32_16x16x32_bf16(a0, bA, acc[t], 0, 0, 0);
            acc[t] = __builtin_amdgcn_mfma_f32_16x16x32_bf16(a1, bB, acc[t], 0, 0, 0);
        }
#pragma unroll
        for (int t = 0; t < 4; t++)
#pragma unroll
            for (int r = 0; r < 4; r++)
                sH[(w * 16 + qd * 4 + r) * HP + t * 16 + m] = f2bf(fmaxf(acc[t][r], 0.f));
    }
    __syncthreads();

    if (!do_final) {
#pragma unroll
        for (int p = 0; p < 2; p++) {
            int idx = tid + p * 256;
            int r = idx >> 3, q = idx & 7;
            if (base + r < n_nodes)
                *(uint4*)(y + (size_t)(base + r) * FDIM + q * 8) = *(uint4*)(&sH[r * HP + q * 8]);
        }
    } else {
        for (int i = tid; i < 64 * 10; i += 256) {
            int nl = i / 10, cc = i % 10;
            int node = base + nl;
            if (node < n_nodes) {
                float s = sbl[cc];
#pragma unroll
                for (int k0 = 0; k0 < FDIM; k0 += 4) {
                    uint2 hp = *(uint2*)(&sH[nl * HP + k0]);
                    s += bflo(hp.x) * sWl[(k0 + 0) * 10 + cc] + bfhi(hp.x) * sWl[(k0 + 1) * 10 + cc]
                       + bflo(hp.y) * sWl[(k0 + 2) * 10 + cc] + bfhi(hp.y) * sWl[(k0 + 3) * 10 + cc];
                }
                out[(size_t)node * 10 + cc] = s;
            }
        }
    }
}

extern "C" void kernel_launch(void* const* d_in, const int* in_sizes, int n_in,
                              void* d_out, int out_size, void* d_ws, size_t ws_size,
                              hipStream_t stream) {
    const float* features = (const float*)d_in[0];
    const int* edges = (const int*)d_in[1];
    int n_nodes = in_sizes[0] / FDIM;          // 50000
    int n_edges = in_sizes[1] / 2;             // 800000
    const int* src = edges;
    const int* dst = edges + n_edges;

    int nbuck = (n_nodes + BNODES - 1) / BNODES;     // 782
    int nchunks = (n_edges + CHUNK - 1) / CHUNK;     // 196

    // workspace: hist | chunk_off | bucket_total | bucket_start | row_ptr | packed | src_sorted | bf16 bufs | wt
    int* hist = (int*)d_ws;
    int* chunk_off = hist + (size_t)nchunks * nbuck;
    int* bucket_total = chunk_off + (size_t)nchunks * nbuck;
    int* bucket_start = bucket_total + nbuck;
    int* row_ptr = bucket_start + nbuck + 1;
    unsigned int* packed = (unsigned int*)(row_ptr + n_nodes + 1);
    int* src_sorted = (int*)(packed + n_edges);
    size_t int_elems = 2 * (size_t)nchunks * nbuck + 2 * (size_t)nbuck + 2
                       + (size_t)n_nodes + 2 * (size_t)n_edges;
    int_elems = (int_elems + 3) & ~(size_t)3;
    size_t buf_elems = (size_t)n_nodes * FDIM;
    unsigned short* hb  = (unsigned short*)((int*)d_ws + int_elems);
    unsigned short* xb0 = hb + buf_elems;
    unsigned short* yA  = xb0 + buf_elems;
    unsigned short* yB  = yA + buf_elems;
    unsigned short* wt  = yB + buf_elems;     // 6 * 4096 bf16 (48 KB)

    dim3 bs(256);
    int n4 = (int)(buf_elems / 4);
    int ncast = (n4 + 255) / 256;          // 3125
    dim3 gs_cp(ncast + 6);
    dim3 gs_gather((n_nodes + 31) / 32);   // 1563
    dim3 gs_tile((n_nodes + 63) / 64);     // 782

    // --- fused cast + weight prep ---
    cast_and_prep<<<gs_cp, bs, 0, stream>>>(features, xb0, n4, ncast,
                                            (const float*)d_in[2], (const float*)d_in[4],
                                            (const float*)d_in[6], (const float*)d_in[8],
                                            (const float*)d_in[10], (const float*)d_in[12], wt);

    // --- build node-grouped CSR via 2-pass bucket sort (deterministic fill) ---
    bucket_hist<<<nchunks, 256, 0, stream>>>(dst, hist, n_edges, nbuck);
    scan_chunks<<<nbuck, 256, 0, stream>>>(hist, chunk_off, bucket_total, nchunks, nbuck);
    scan_buckets<<<1, 1024, 0, stream>>>(bucket_total, bucket_start, row_ptr, nbuck, n_nodes, n_edges);
    bucket_fill<<<nchunks, 256, 0, stream>>>(src, dst, bucket_start, chunk_off, packed, n_edges, nbuck);
    sort_bucket<<<nbuck, 256, 0, stream>>>(packed, bucket_start, src_sorted, row_ptr, n_nodes);

    // --- 3 GIN convs, split gather/MFMA-MLP (last MLP fuses the final linear) ---
    const float* Wl = (const float*)d_in[14];
    const float* bl = (const float*)d_in[15];
    const unsigned short* x_cur = xb0;
    unsigned short* outs[3] = {yA, yB, yA};
    for (int conv = 0; conv < 3; conv++) {
        const float* b1 = (const float*)d_in[3 + 4 * conv];
        const float* b2 = (const float*)d_in[5 + 4 * conv];
        const unsigned short* wt1 = wt + (size_t)(2 * conv) * 4096;
        const unsigned short* wt2 = wt + (size_t)(2 * conv + 1) * 4096;
        int fin = (conv == 2) ? 1 : 0;

        gather_bf16<<<gs_gather, bs, 0, stream>>>(x_cur, row_ptr, src_sorted, hb, n_nodes);
        mlp_mfma<<<gs_tile, bs, 0, stream>>>(hb, wt1, b1, wt2, b2, Wl, bl,
                                             outs[conv], (float*)d_out, n_nodes, fin);
        x_cur = outs[conv];
    }
}